// Round 5
// baseline (14029.900 us; speedup 1.0000x reference)
//
#include <hip/hip_runtime.h>

typedef __attribute__((ext_vector_type(4))) float  f32x4;
typedef __attribute__((ext_vector_type(8))) short  bf16x8;

#define NTHR 1024
#define BT   128

// ---------------- LDS byte map (total 133024 <= 163840) ----------------
// planes: [layer][split] 16384B each: [128 elems][64 units] bf16, XOR-swizzled
#define PLANE(L,S) ((L)*32768 + (S)*16384)
#define XFB_OFF    98304                   // [128][3] f32 feedback x (1536B)
#define Y1_OFF     99840                   // [128][34] bf16 (8704B)
#define Y2_OFF     108544                  // [128][18] bf16 (4608B)
#define W2L_OFF    113152                  // [16][32] bf16 (1024B)
#define BGL_OFF    114176                  // [3][256] f32 bias sums (3072B)
#define B1L_OFF    117248                  // [32] f32
#define B2L_OFF    117376                  // [16] f32
#define B3L_OFF    117440                  // [4] f32
#define W3L_OFF    117456                  // [3][16] f32 (192B)
#define W0L_OFF    117664                  // [256][3] f32 (3072B)
#define OUT_OFF    120736                  // [128][24] f32 out ring, 8 steps (12288B)
#define LDS_TOTAL  133024

// frag-ordered split weights: 5 gate mats * 64KB + w1 8KB
__device__ __align__(16) unsigned char g_wsbuf[335872];

__device__ __forceinline__ unsigned short f2bf(float v) {
    unsigned int x = __float_as_uint(v);
    unsigned int r = x + 0x7fffu + ((x >> 16) & 1u);
    return (unsigned short)(r >> 16);
}
__device__ __forceinline__ float bf2f_lo(unsigned int d) { return __uint_as_float(d << 16); }
__device__ __forceinline__ float bf2f_hi(unsigned int d) { return __uint_as_float(d & 0xffff0000u); }

__device__ __forceinline__ float fsig(float x) {
    return __builtin_amdgcn_rcpf(1.0f + __expf(-x));
}
__device__ __forceinline__ float ftanh(float x) {
    float e = __expf(2.0f * x);
    return 1.0f - 2.0f * __builtin_amdgcn_rcpf(e + 1.0f);
}

// ---------------- prologue: frag-order + split weights (layout unchanged) ----------------
__global__ void prep_weights(const float* __restrict__ whh0, const float* __restrict__ wih1,
                             const float* __restrict__ whh1, const float* __restrict__ wih2,
                             const float* __restrict__ whh2, const float* __restrict__ w1g)
{
    int gi = blockIdx.x * 256 + threadIdx.x;
    if (gi < 20480) {
        int m = gi >> 12;
        int rem = gi & 4095;
        int b = rem >> 6, l = rem & 63;
        int s = b & 1, ks = (b >> 1) & 1, g = (b >> 2) & 3, ug = b >> 4;
        int row = g * 64 + ug * 16 + (l & 15);
        int kb  = ks * 32 + (l >> 4) * 8;
        const float* src = (m == 0) ? whh0 : (m == 1) ? wih1 : (m == 2) ? whh1
                         : (m == 3) ? wih2 : whh2;
        unsigned short o[8];
        #pragma unroll
        for (int i = 0; i < 8; ++i) {
            float v = src[row * 64 + kb + i];
            unsigned short hh = f2bf(v);
            if (s) {
                float r2 = v - __uint_as_float((unsigned int)hh << 16);
                hh = f2bf(r2);
            }
            o[i] = hh;
        }
        unsigned char* dst = g_wsbuf + m * 65536 + b * 1024 + l * 16;
        #pragma unroll
        for (int i = 0; i < 8; ++i) ((unsigned short*)dst)[i] = o[i];
    } else if (gi < 20992) {
        int g2 = gi - 20480;
        int b = g2 >> 6, l = g2 & 63;
        int s = b & 1, ks = (b >> 1) & 1, nt = b >> 2;
        int row = nt * 16 + (l & 15);
        int kb  = ks * 32 + (l >> 4) * 8;
        unsigned short o[8];
        #pragma unroll
        for (int i = 0; i < 8; ++i) {
            float v = w1g[row * 64 + kb + i];
            unsigned short hh = f2bf(v);
            if (s) {
                float r2 = v - __uint_as_float((unsigned int)hh << 16);
                hh = f2bf(r2);
            }
            o[i] = hh;
        }
        unsigned char* dst = g_wsbuf + 327680 + b * 1024 + l * 16;
        #pragma unroll
        for (int i = 0; i < 8; ++i) ((unsigned short*)dst)[i] = o[i];
    }
}

#define MFMA_(A,B,C) __builtin_amdgcn_mfma_f32_16x16x32_bf16(A, B, C, 0, 0, 0)

// direct global->reg B-fragment group (4 frags = this wave's ug slice of one quarter)
#define LOADG(m, ks, s, Rn) do { \
    Rn##0 = *(const bf16x8*)(g_wsbuf + (m) * 65536 + ((ug * 4 + 0) * 4 + (ks) * 2 + (s)) * 1024 + lane * 16); \
    Rn##1 = *(const bf16x8*)(g_wsbuf + (m) * 65536 + ((ug * 4 + 1) * 4 + (ks) * 2 + (s)) * 1024 + lane * 16); \
    Rn##2 = *(const bf16x8*)(g_wsbuf + (m) * 65536 + ((ug * 4 + 2) * 4 + (ks) * 2 + (s)) * 1024 + lane * 16); \
    Rn##3 = *(const bf16x8*)(g_wsbuf + (m) * 65536 + ((ug * 4 + 3) * 4 + (ks) * 2 + (s)) * 1024 + lane * 16); \
    } while (0)

#define LOADW1G(Rn) do { \
    Rn##0 = *(const bf16x8*)(g_wsbuf + 327680 + (hf * 4 + 0) * 1024 + lane * 16); \
    Rn##1 = *(const bf16x8*)(g_wsbuf + 327680 + (hf * 4 + 1) * 1024 + lane * 16); \
    Rn##2 = *(const bf16x8*)(g_wsbuf + 327680 + (hf * 4 + 2) * 1024 + lane * 16); \
    Rn##3 = *(const bf16x8*)(g_wsbuf + 327680 + (hf * 4 + 3) * 1024 + lane * 16); \
    } while (0)

#define ACC_INIT(L) do { \
    _Pragma("unroll") for (int g_ = 0; g_ < 4; ++g_) { \
        float b_ = *(const float*)(lds + BGL_OFF + ((L) * 256 + g_ * 64 + u) * 4); \
        f32x4 t_ = {b_, b_, b_, b_}; \
        _Pragma("unroll") for (int mt_ = 0; mt_ < 2; ++mt_) acc[g_][mt_] = t_; \
    } } while (0)

// hi pass: acc += ah*Bhi + al*Bhi   (16 MFMA)
#define GHI(APL, ks, Rn) do { \
    _Pragma("unroll") for (int mt_ = 0; mt_ < 2; ++mt_) { \
        int ab_ = (((mbase + mt_ * 16 + l15) * 128 + (ks) * 64 + l4 * 16)) ^ rswz; \
        bf16x8 ah_ = *(const bf16x8*)(lds + PLANE(APL, 0) + ab_); \
        bf16x8 al_ = *(const bf16x8*)(lds + PLANE(APL, 1) + ab_); \
        acc[0][mt_] = MFMA_(ah_, Rn##0, acc[0][mt_]); acc[0][mt_] = MFMA_(al_, Rn##0, acc[0][mt_]); \
        acc[1][mt_] = MFMA_(ah_, Rn##1, acc[1][mt_]); acc[1][mt_] = MFMA_(al_, Rn##1, acc[1][mt_]); \
        acc[2][mt_] = MFMA_(ah_, Rn##2, acc[2][mt_]); acc[2][mt_] = MFMA_(al_, Rn##2, acc[2][mt_]); \
        acc[3][mt_] = MFMA_(ah_, Rn##3, acc[3][mt_]); acc[3][mt_] = MFMA_(al_, Rn##3, acc[3][mt_]); \
    } } while (0)

// lo pass: acc += ah*Blo   (8 MFMA)
#define GLO(APL, ks, Rn) do { \
    _Pragma("unroll") for (int mt_ = 0; mt_ < 2; ++mt_) { \
        int ab_ = (((mbase + mt_ * 16 + l15) * 128 + (ks) * 64 + l4 * 16)) ^ rswz; \
        bf16x8 ah_ = *(const bf16x8*)(lds + PLANE(APL, 0) + ab_); \
        acc[0][mt_] = MFMA_(ah_, Rn##0, acc[0][mt_]); \
        acc[1][mt_] = MFMA_(ah_, Rn##1, acc[1][mt_]); \
        acc[2][mt_] = MFMA_(ah_, Rn##2, acc[2][mt_]); \
        acc[3][mt_] = MFMA_(ah_, Rn##3, acc[3][mt_]); \
    } } while (0)

#define CELLW(L, CARR) do { \
    _Pragma("unroll") for (int mt_ = 0; mt_ < 2; ++mt_) \
    _Pragma("unroll") for (int r_ = 0; r_ < 4; ++r_) { \
        float gi_ = fsig(acc[0][mt_][r_]); \
        float gf_ = fsig(acc[1][mt_][r_]); \
        float gg_ = ftanh(acc[2][mt_][r_]); \
        float go_ = fsig(acc[3][mt_][r_]); \
        float cn_ = gf_ * CARR[mt_ * 4 + r_] + gi_ * gg_; \
        CARR[mt_ * 4 + r_] = cn_; \
        float hn_ = go_ * ftanh(cn_); \
        int e_ = mbase + mt_ * 16 + l4 * 4 + r_; \
        int wb_ = ((e_ * 128 + u * 2)) ^ ((e_ & 7) << 4); \
        unsigned short hh_ = f2bf(hn_); \
        float hf2_ = __uint_as_float((unsigned int)hh_ << 16); \
        unsigned short hl_ = f2bf(hn_ - hf2_); \
        *(unsigned short*)(lds + PLANE(L, 0) + wb_) = hh_; \
        *(unsigned short*)(lds + PLANE(L, 1) + wb_) = hl_; \
    } } while (0)

#define XPART do { \
    _Pragma("unroll") for (int mt_ = 0; mt_ < 2; ++mt_) \
    _Pragma("unroll") for (int r_ = 0; r_ < 4; ++r_) { \
        int e_ = mbase + mt_ * 16 + l4 * 4 + r_; \
        const float* xp_ = (const float*)(lds + XFB_OFF + e_ * 12); \
        float x0_ = xp_[0], x1_ = xp_[1], x2_ = xp_[2]; \
        _Pragma("unroll") for (int g_ = 0; g_ < 4; ++g_) { \
            const float* w0_ = (const float*)(lds + W0L_OFF + (g_ * 64 + u) * 12); \
            acc[g_][mt_][r_] += x0_ * w0_[0] + x1_ * w0_[1] + x2_ * w0_[2]; \
        } } } while (0)

// w1 frag regs: Rn0 = (ks0,hi), Rn1 = (ks0,lo), Rn2 = (ks1,hi), Rn3 = (ks1,lo)
#define MLP1G(Rn) do { \
    float b1_ = *(const float*)(lds + B1L_OFF + (hf * 16 + l15) * 4); \
    f32x4 a1_ = {b1_, b1_, b1_, b1_}; \
    { int ab_ = (((Mt * 16 + l15) * 128 + 0 * 64 + l4 * 16)) ^ rswz; \
      bf16x8 ah_ = *(const bf16x8*)(lds + PLANE(2, 0) + ab_); \
      bf16x8 al_ = *(const bf16x8*)(lds + PLANE(2, 1) + ab_); \
      a1_ = MFMA_(ah_, Rn##0, a1_); a1_ = MFMA_(al_, Rn##0, a1_); a1_ = MFMA_(ah_, Rn##1, a1_); } \
    { int ab_ = (((Mt * 16 + l15) * 128 + 1 * 64 + l4 * 16)) ^ rswz; \
      bf16x8 ah_ = *(const bf16x8*)(lds + PLANE(2, 0) + ab_); \
      bf16x8 al_ = *(const bf16x8*)(lds + PLANE(2, 1) + ab_); \
      a1_ = MFMA_(ah_, Rn##2, a1_); a1_ = MFMA_(al_, Rn##2, a1_); a1_ = MFMA_(ah_, Rn##3, a1_); } \
    _Pragma("unroll") for (int r_ = 0; r_ < 4; ++r_) { \
        float y_ = a1_[r_]; y_ = (y_ >= 0.f) ? y_ : 0.01f * y_; \
        int e_ = Mt * 16 + l4 * 4 + r_; \
        *(unsigned short*)(lds + Y1_OFF + e_ * 68 + hf * 32 + l15 * 2) = f2bf(y_); \
    } } while (0)

#define MLP2 do { \
    int e2_ = tid & 127, rg_ = tid >> 7; \
    float a2_[2]; \
    _Pragma("unroll") for (int m_ = 0; m_ < 2; ++m_) \
        a2_[m_] = *(const float*)(lds + B2L_OFF + (rg_ * 2 + m_) * 4); \
    _Pragma("unroll") for (int kd_ = 0; kd_ < 16; ++kd_) { \
        unsigned int d_ = *(const unsigned int*)(lds + Y1_OFF + e2_ * 68 + kd_ * 4); \
        float v0_ = bf2f_lo(d_), v1_ = bf2f_hi(d_); \
        _Pragma("unroll") for (int m_ = 0; m_ < 2; ++m_) { \
            unsigned int w_ = *(const unsigned int*)(lds + W2L_OFF + ((rg_ * 2 + m_) * 32 + kd_ * 2) * 2); \
            a2_[m_] = fmaf(v0_, bf2f_lo(w_), a2_[m_]); \
            a2_[m_] = fmaf(v1_, bf2f_hi(w_), a2_[m_]); \
        } } \
    _Pragma("unroll") for (int m_ = 0; m_ < 2; ++m_) { \
        float y_ = a2_[m_]; y_ = (y_ >= 0.f) ? y_ : 0.01f * y_; \
        *(unsigned short*)(lds + Y2_OFF + e2_ * 36 + (rg_ * 2 + m_) * 2) = f2bf(y_); \
    } } while (0)

#define MLP3_OUT do { \
    if (tid < 384) { \
        int e3_ = tid & 127, r3_ = tid >> 7; \
        float a3_ = *(const float*)(lds + B3L_OFF + r3_ * 4); \
        _Pragma("unroll") for (int kd_ = 0; kd_ < 8; ++kd_) { \
            unsigned int d_ = *(const unsigned int*)(lds + Y2_OFF + e3_ * 36 + kd_ * 4); \
            a3_ = fmaf(bf2f_lo(d_), *(const float*)(lds + W3L_OFF + (r3_ * 16 + kd_ * 2) * 4),     a3_); \
            a3_ = fmaf(bf2f_hi(d_), *(const float*)(lds + W3L_OFF + (r3_ * 16 + kd_ * 2 + 1) * 4), a3_); \
        } \
        float y_ = (a3_ >= 0.f) ? a3_ : 0.01f * a3_; \
        *(float*)(lds + XFB_OFF + e3_ * 12 + r3_ * 4) = y_; \
        *(float*)(lds + OUT_OFF + e3_ * 96 + (t & 7) * 12 + r3_ * 4) = y_; \
    } } while (0)

// ---------------- main persistent kernel ----------------
extern "C" __global__ void __launch_bounds__(NTHR, 4)
lstm_mfma(const float* __restrict__ noise,
          const float* __restrict__ wih0, const float* __restrict__ whh0,
          const float* __restrict__ bih0, const float* __restrict__ bhh0,
          const float* __restrict__ wih1, const float* __restrict__ whh1,
          const float* __restrict__ bih1, const float* __restrict__ bhh1,
          const float* __restrict__ wih2, const float* __restrict__ whh2,
          const float* __restrict__ bih2, const float* __restrict__ bhh2,
          const float* __restrict__ w1g, const float* __restrict__ b1g,
          const float* __restrict__ w2g, const float* __restrict__ b2g,
          const float* __restrict__ w3g, const float* __restrict__ b3g,
          const int* __restrict__ lenp, float* __restrict__ out)
{
    extern __shared__ unsigned char lds[];
    const int tid  = threadIdx.x;
    const int lane = tid & 63;
    const int wv   = tid >> 6;       // wave 0..15
    const int ug   = wv & 3;         // unit group (16 units)
    const int mh   = wv >> 2;        // M quarter 0..3
    const int l15  = lane & 15;
    const int l4   = lane >> 4;      // k-group
    const int u    = ug * 16 + l15;  // unit 0..63
    const int mbase = mh * 32;
    const int rswz  = (lane & 7) << 4;
    const int hf    = wv & 1;        // MLP1 half
    const int Mt    = wv >> 1;       // MLP1 M-tile
    const int T = *lenp;
    const long eg0  = (long)blockIdx.x * BT;
    const long outs = 3L * T;

    // per-thread recurrent c state
    float c0[8], c1[8], c2[8];
    #pragma unroll
    for (int i = 0; i < 8; ++i) { c0[i] = 0.f; c1[i] = 0.f; c2[i] = 0.f; }

    // B-fragment register ring (3 groups x 4 frags)
    bf16x8 RGa0, RGa1, RGa2, RGa3;
    bf16x8 RGb0, RGb1, RGb2, RGb3;
    bf16x8 RGc0, RGc1, RGc2, RGc3;

    // warmup loads: G0 (whh0 hi ks0), G1 (hi ks1), G2 (lo ks0)
    LOADG(0, 0, 0, RGa);
    LOADG(0, 1, 0, RGb);
    LOADG(0, 0, 1, RGc);

    // ---- LDS init ----
    for (int i = tid; i < 98304 / 4; i += NTHR) ((unsigned int*)lds)[i] = 0u;  // h planes = 0
    if (tid < BT) {
        #pragma unroll
        for (int k = 0; k < 3; ++k)
            *(float*)(lds + XFB_OFF + tid * 12 + k * 4) = noise[(eg0 + tid) * 3 + k];
    }
    if (tid < 512) *(unsigned short*)(lds + W2L_OFF + tid * 2) = f2bf(w2g[tid]);
    if (tid < 768) {                                   // bias sums
        int l = tid >> 8, r = tid & 255;
        const float* bi = (l == 0) ? bih0 : ((l == 1) ? bih1 : bih2);
        const float* bh = (l == 0) ? bhh0 : ((l == 1) ? bhh1 : bhh2);
        *(float*)(lds + BGL_OFF + tid * 4) = bi[r] + bh[r];
    }
    if (tid < 768) *(float*)(lds + W0L_OFF + tid * 4) = wih0[tid];  // [256][3]
    if (tid < 32) *(float*)(lds + B1L_OFF + tid * 4) = b1g[tid];
    if (tid < 16) *(float*)(lds + B2L_OFF + tid * 4) = b2g[tid];
    if (tid < 3)  *(float*)(lds + B3L_OFF + tid * 4) = b3g[tid];
    if (tid < 48) *(float*)(lds + W3L_OFF + tid * 4) = w3g[tid];

    __syncthreads();                 // init visible

    f32x4 acc[4][2];

    #pragma unroll 1
    for (int t = 0; t < T; ++t) {
        // ------------- layer 0: gates = wih0*x + whh0*h0_old -------------
        ACC_INIT(0); XPART;
        GHI(0, 0, RGa);  LOADG(0, 1, 1, RGa);   // G0 ; load G3
        GHI(0, 1, RGb);  LOADG(1, 0, 0, RGb);   // G1 ; load G4
        GLO(0, 0, RGc);  LOADG(1, 1, 0, RGc);   // G2 ; load G5
        GLO(0, 1, RGa);  LOADG(1, 0, 1, RGa);   // G3 ; load G6
        __syncthreads();
        CELLW(0, c0);                           // h0 -> plane0
        __syncthreads();
        // ------------- layer 1: wih1*h0_new + whh1*h1_old -------------
        ACC_INIT(1);
        GHI(0, 0, RGb);  LOADG(1, 1, 1, RGb);   // G4 ; load G7
        GHI(0, 1, RGc);  LOADG(2, 0, 0, RGc);   // G5 ; load G8
        GLO(0, 0, RGa);  LOADG(2, 1, 0, RGa);   // G6 ; load G9
        GLO(0, 1, RGb);  LOADG(2, 0, 1, RGb);   // G7 ; load G10
        GHI(1, 0, RGc);  LOADG(2, 1, 1, RGc);   // G8 ; load G11
        GHI(1, 1, RGa);  LOADG(3, 0, 0, RGa);   // G9 ; load G12
        GLO(1, 0, RGb);  LOADG(3, 1, 0, RGb);   // G10; load G13
        GLO(1, 1, RGc);  LOADG(3, 0, 1, RGc);   // G11; load G14
        __syncthreads();
        CELLW(1, c1);                           // h1 -> plane1
        __syncthreads();
        // ------------- layer 2: wih2*h1_new + whh2*h2_old -------------
        ACC_INIT(2);
        GHI(1, 0, RGa);  LOADG(3, 1, 1, RGa);   // G12; load G15
        GHI(1, 1, RGb);  LOADG(4, 0, 0, RGb);   // G13; load G16
        GLO(1, 0, RGc);  LOADG(4, 1, 0, RGc);   // G14; load G17
        GLO(1, 1, RGa);  LOADG(4, 0, 1, RGa);   // G15; load G18
        GHI(2, 0, RGb);  LOADG(4, 1, 1, RGb);   // G16; load G19
        GHI(2, 1, RGc);  LOADW1G(RGc);          // G17; load G20 (w1)
        GLO(2, 0, RGa);  LOADG(0, 0, 0, RGa);   // G18; load G0' (next step)
        GLO(2, 1, RGb);  LOADG(0, 1, 0, RGb);   // G19; load G1'
        __syncthreads();
        CELLW(2, c2);                           // h2 -> plane2
        __syncthreads();
        // ------------- MLP head -------------
        MLP1G(RGc);      LOADG(0, 0, 1, RGc);   // G20; load G2'
        __syncthreads();
        MLP2;
        __syncthreads();
        MLP3_OUT;
        if ((t & 7) == 7) {                     // flush 8 buffered steps
            __syncthreads();
            long tb = t - 7;
            #pragma unroll
            for (int it = 0; it < 3; ++it) {
                int i = it * NTHR + tid;        // 0..3071
                int e = i / 24, j = i - e * 24;
                out[(eg0 + e) * outs + tb * 3 + j] =
                    *(const float*)(lds + OUT_OFF + e * 96 + j * 4);
            }
        }
        __syncthreads();                        // step boundary
    }

    // tail flush (T not multiple of 8)
    int nst = T & 7;
    if (nst) {
        int nfl = BT * nst * 3;
        for (int i = tid; i < nfl; i += NTHR) {
            int e = i / (nst * 3), j = i - e * (nst * 3);
            out[(eg0 + e) * outs + (long)(T - nst) * 3 + j] =
                *(const float*)(lds + OUT_OFF + e * 96 + j * 4);
        }
    }
}

extern "C" void kernel_launch(void* const* d_in, const int* in_sizes, int n_in,
                              void* d_out, int out_size, void* d_ws, size_t ws_size,
                              hipStream_t stream)
{
    const float* noise = (const float*)d_in[0];
    const float* wih0  = (const float*)d_in[1];
    const float* whh0  = (const float*)d_in[2];
    const float* bih0  = (const float*)d_in[3];
    const float* bhh0  = (const float*)d_in[4];
    const float* wih1  = (const float*)d_in[5];
    const float* whh1  = (const float*)d_in[6];
    const float* bih1  = (const float*)d_in[7];
    const float* bhh1  = (const float*)d_in[8];
    const float* wih2  = (const float*)d_in[9];
    const float* whh2  = (const float*)d_in[10];
    const float* bih2  = (const float*)d_in[11];
    const float* bhh2  = (const float*)d_in[12];
    const float* w1g   = (const float*)d_in[13];
    const float* b1g   = (const float*)d_in[14];
    const float* w2g   = (const float*)d_in[15];
    const float* b2g   = (const float*)d_in[16];
    const float* w3g   = (const float*)d_in[17];
    const float* b3g   = (const float*)d_in[18];
    const int*   lenp  = (const int*)d_in[19];
    float* out = (float*)d_out;

    int B = in_sizes[0] / 3;              // 32768
    int grid = B / BT;                    // 256 blocks = 1 per CU

    prep_weights<<<82, 256, 0, stream>>>(whh0, wih1, whh1, wih2, whh2, w1g);

    hipFuncSetAttribute((const void*)lstm_mfma,
                        hipFuncAttributeMaxDynamicSharedMemorySize, LDS_TOTAL);
    lstm_mfma<<<grid, NTHR, LDS_TOTAL, stream>>>(
        noise, wih0, whh0, bih0, bhh0, wih1, whh1, bih1, bhh1,
        wih2, whh2, bih2, bhh2, w1g, b1g, w2g, b2g, w3g, b3g, lenp, out);
}

// Round 6
// 9567.388 us; speedup vs baseline: 1.4664x; 1.4664x over previous
//
#include <hip/hip_runtime.h>

typedef __attribute__((ext_vector_type(4))) float  f32x4;
typedef __attribute__((ext_vector_type(8))) short  bf16x8;

#define NTHR 1024
#define BT   128
#define L2E  1.4426950408889634f

// ---------------- LDS byte map (total 162704 <= 163840) ----------------
// planes: [layer][split] 16384B each: [128 elems][64 units] bf16, XOR-swizzled
#define PLANE(L,S) ((L)*32768 + (S)*16384)
#define QB(s)      (98304 + (s)*16384)     // 3-slot staging ring (48KB)
#define Y1_OFF     114688                  // alias: slot1 + 0      [128][34] bf16 (8704B), live k23-k25
#define Y2_OFF     123392                  // alias: slot1 + 8704   [128][18] bf16 (4608B), live k24-k26
#define XFB_OFF    147456                  // [128][3] f32 feedback x (1536B)
#define W2L_OFF    148992                  // [16][32] bf16 (1024B)
#define BGL_OFF    150016                  // [3][256] f32 bias sums, log2e-scaled (3072B)
#define B1L_OFF    153088                  // [32] f32
#define B2L_OFF    153216                  // [16] f32
#define B3L_OFF    153280                  // [4] f32
#define W3L_OFF    153296                  // [3][16] f32 (192B)
#define W0L_OFF    153488                  // [256][3] f32, log2e-scaled (3072B)
#define OUT_OFF    156560                  // [128][4][3] f32 out ring (6144B)
#define LDS_TOTAL  162704

// frag-ordered split weights (log2e-prescaled): 5 gate mats * 64KB + w1 8KB
__device__ __align__(16) unsigned char g_wsbuf[335872];

__device__ __forceinline__ unsigned short f2bf(float v) {
    unsigned int x = __float_as_uint(v);
    unsigned int r = x + 0x7fffu + ((x >> 16) & 1u);
    return (unsigned short)(r >> 16);
}
__device__ __forceinline__ float bf2f_lo(unsigned int d) { return __uint_as_float(d << 16); }
__device__ __forceinline__ float bf2f_hi(unsigned int d) { return __uint_as_float(d & 0xffff0000u); }

// gates pre-scaled by log2e (2*log2e for g-gate): pure exp2 forms
__device__ __forceinline__ float fsig2(float y) {   // sigmoid(x), y = x*log2e
    return __builtin_amdgcn_rcpf(1.0f + __builtin_amdgcn_exp2f(-y));
}
__device__ __forceinline__ float ftanh2(float y) {  // tanh(x), y = 2x*log2e
    return 1.0f - 2.0f * __builtin_amdgcn_rcpf(1.0f + __builtin_amdgcn_exp2f(y));
}
__device__ __forceinline__ float ftanhc(float c) {  // tanh(c), c true-scale
    return 1.0f - 2.0f * __builtin_amdgcn_rcpf(1.0f + __builtin_amdgcn_exp2f(c * (2.0f * L2E)));
}

// ---------------- prologue: frag-order + split + log2e-prescale ----------------
__global__ void prep_weights(const float* __restrict__ whh0, const float* __restrict__ wih1,
                             const float* __restrict__ whh1, const float* __restrict__ wih2,
                             const float* __restrict__ whh2, const float* __restrict__ w1g)
{
    int gi = blockIdx.x * 256 + threadIdx.x;
    if (gi < 20480) {
        int m = gi >> 12;
        int rem = gi & 4095;
        int b = rem >> 6, l = rem & 63;
        int s = b & 1, ks = (b >> 1) & 1, g = (b >> 2) & 3, ug = b >> 4;
        int row = g * 64 + ug * 16 + (l & 15);
        int kb  = ks * 32 + (l >> 4) * 8;
        float fac = (g == 2) ? (2.0f * L2E) : L2E;
        const float* src = (m == 0) ? whh0 : (m == 1) ? wih1 : (m == 2) ? whh1
                         : (m == 3) ? wih2 : whh2;
        unsigned short o[8];
        #pragma unroll
        for (int i = 0; i < 8; ++i) {
            float v = src[row * 64 + kb + i] * fac;
            unsigned short hh = f2bf(v);
            if (s) {
                float r2 = v - __uint_as_float((unsigned int)hh << 16);
                hh = f2bf(r2);
            }
            o[i] = hh;
        }
        unsigned char* dst = g_wsbuf + m * 65536 + b * 1024 + l * 16;
        #pragma unroll
        for (int i = 0; i < 8; ++i) ((unsigned short*)dst)[i] = o[i];
    } else if (gi < 20992) {
        int g2 = gi - 20480;
        int b = g2 >> 6, l = g2 & 63;
        int s = b & 1;
        int ks = (b >> 1) & 1, nt = b >> 2;
        int row = nt * 16 + (l & 15);
        int kb  = ks * 32 + (l >> 4) * 8;
        unsigned short o[8];
        #pragma unroll
        for (int i = 0; i < 8; ++i) {
            float v = w1g[row * 64 + kb + i];           // w1: unscaled
            unsigned short hh = f2bf(v);
            if (s) {
                float r2 = v - __uint_as_float((unsigned int)hh << 16);
                hh = f2bf(r2);
            }
            o[i] = hh;
        }
        unsigned char* dst = g_wsbuf + 327680 + b * 1024 + l * 16;
        #pragma unroll
        for (int i = 0; i < 8; ++i) ((unsigned short*)dst)[i] = o[i];
    }
}

#define MFMA_(A,B,C) __builtin_amdgcn_mfma_f32_16x16x32_bf16(A, B, C, 0, 0, 0)

// commit pending reg R to ring slot, then load next quarter (m,ks,s) into R
#define CL(SLOT, mm, kks, ss) do { \
    *(bf16x8*)(lds + QB(SLOT) + tid * 16) = R; \
    R = *(const bf16x8*)(g_wsbuf + (mm) * 65536 + \
        ((tid >> 6) * 4 + (kks) * 2 + (ss)) * 1024 + (tid & 63) * 16); \
    } while (0)
#define CLW1(SLOT) do { \
    *(bf16x8*)(lds + QB(SLOT) + tid * 16) = R; \
    if (tid < 512) \
        R = *(const bf16x8*)(g_wsbuf + 327680 + (tid >> 6) * 1024 + (tid & 63) * 16); \
    } while (0)

#define ACC_(L) do { \
    _Pragma("unroll") for (int g_ = 0; g_ < 4; ++g_) { \
        float b_ = *(const float*)(lds + BGL_OFF + ((L) * 256 + g_ * 64 + u) * 4); \
        f32x4 t_ = {b_, b_, b_, b_}; \
        acc[g_][0] = t_; acc[g_][1] = t_; \
    } } while (0)

#define XPART_ do { \
    _Pragma("unroll") for (int mt_ = 0; mt_ < 2; ++mt_) \
    _Pragma("unroll") for (int r_ = 0; r_ < 4; ++r_) { \
        int e_ = mbase + mt_ * 16 + l4 * 4 + r_; \
        const float* xp_ = (const float*)(lds + XFB_OFF + e_ * 12); \
        float x0_ = xp_[0], x1_ = xp_[1], x2_ = xp_[2]; \
        _Pragma("unroll") for (int g_ = 0; g_ < 4; ++g_) { \
            const float* w0_ = (const float*)(lds + W0L_OFF + (g_ * 64 + u) * 12); \
            acc[g_][mt_][r_] += x0_ * w0_[0] + x1_ * w0_[1] + x2_ * w0_[2]; \
        } } } while (0)

// hi pass: acc += (ah+al)*Bhi; keeps ah in ahk0/ahk1 for the next GLO_ phase
#define GHI_(APL, ks, SLOT) do { \
    bf16x8 b0_ = *(const bf16x8*)(lds + QB(SLOT) + (ug * 4 + 0) * 1024 + lane * 16); \
    bf16x8 b1_ = *(const bf16x8*)(lds + QB(SLOT) + (ug * 4 + 1) * 1024 + lane * 16); \
    bf16x8 b2_ = *(const bf16x8*)(lds + QB(SLOT) + (ug * 4 + 2) * 1024 + lane * 16); \
    bf16x8 b3_ = *(const bf16x8*)(lds + QB(SLOT) + (ug * 4 + 3) * 1024 + lane * 16); \
    { int ab_ = (((mbase + l15) * 128 + (ks) * 64 + l4 * 16)) ^ rswz; \
      ahk0 = *(const bf16x8*)(lds + PLANE(APL, 0) + ab_); \
      bf16x8 al_ = *(const bf16x8*)(lds + PLANE(APL, 1) + ab_); \
      acc[0][0] = MFMA_(ahk0, b0_, acc[0][0]); acc[0][0] = MFMA_(al_, b0_, acc[0][0]); \
      acc[1][0] = MFMA_(ahk0, b1_, acc[1][0]); acc[1][0] = MFMA_(al_, b1_, acc[1][0]); \
      acc[2][0] = MFMA_(ahk0, b2_, acc[2][0]); acc[2][0] = MFMA_(al_, b2_, acc[2][0]); \
      acc[3][0] = MFMA_(ahk0, b3_, acc[3][0]); acc[3][0] = MFMA_(al_, b3_, acc[3][0]); } \
    { int ab_ = (((mbase + 16 + l15) * 128 + (ks) * 64 + l4 * 16)) ^ rswz; \
      ahk1 = *(const bf16x8*)(lds + PLANE(APL, 0) + ab_); \
      bf16x8 al_ = *(const bf16x8*)(lds + PLANE(APL, 1) + ab_); \
      acc[0][1] = MFMA_(ahk1, b0_, acc[0][1]); acc[0][1] = MFMA_(al_, b0_, acc[0][1]); \
      acc[1][1] = MFMA_(ahk1, b1_, acc[1][1]); acc[1][1] = MFMA_(al_, b1_, acc[1][1]); \
      acc[2][1] = MFMA_(ahk1, b2_, acc[2][1]); acc[2][1] = MFMA_(al_, b2_, acc[2][1]); \
      acc[3][1] = MFMA_(ahk1, b3_, acc[3][1]); acc[3][1] = MFMA_(al_, b3_, acc[3][1]); } \
    } while (0)

// lo pass: acc += ah*Blo, ah from the registers saved by the preceding GHI_
#define GLO_(SLOT) do { \
    bf16x8 b0_ = *(const bf16x8*)(lds + QB(SLOT) + (ug * 4 + 0) * 1024 + lane * 16); \
    bf16x8 b1_ = *(const bf16x8*)(lds + QB(SLOT) + (ug * 4 + 1) * 1024 + lane * 16); \
    bf16x8 b2_ = *(const bf16x8*)(lds + QB(SLOT) + (ug * 4 + 2) * 1024 + lane * 16); \
    bf16x8 b3_ = *(const bf16x8*)(lds + QB(SLOT) + (ug * 4 + 3) * 1024 + lane * 16); \
    acc[0][0] = MFMA_(ahk0, b0_, acc[0][0]); acc[0][1] = MFMA_(ahk1, b0_, acc[0][1]); \
    acc[1][0] = MFMA_(ahk0, b1_, acc[1][0]); acc[1][1] = MFMA_(ahk1, b1_, acc[1][1]); \
    acc[2][0] = MFMA_(ahk0, b2_, acc[2][0]); acc[2][1] = MFMA_(ahk1, b2_, acc[2][1]); \
    acc[3][0] = MFMA_(ahk0, b3_, acc[3][0]); acc[3][1] = MFMA_(ahk1, b3_, acc[3][1]); \
    } while (0)

#define CELL_(L, CARR) do { \
    _Pragma("unroll") for (int mt_ = 0; mt_ < 2; ++mt_) \
    _Pragma("unroll") for (int r_ = 0; r_ < 4; ++r_) { \
        float gi_ = fsig2(acc[0][mt_][r_]); \
        float gf_ = fsig2(acc[1][mt_][r_]); \
        float gg_ = ftanh2(acc[2][mt_][r_]); \
        float go_ = fsig2(acc[3][mt_][r_]); \
        float cn_ = gf_ * CARR[mt_ * 4 + r_] + gi_ * gg_; \
        CARR[mt_ * 4 + r_] = cn_; \
        float hn_ = go_ * ftanhc(cn_); \
        int e_ = mbase + mt_ * 16 + l4 * 4 + r_; \
        int wb_ = ((e_ * 128 + u * 2)) ^ ((e_ & 7) << 4); \
        unsigned short hh_ = f2bf(hn_); \
        float hf2_ = __uint_as_float((unsigned int)hh_ << 16); \
        unsigned short hl_ = f2bf(hn_ - hf2_); \
        *(unsigned short*)(lds + PLANE(L, 0) + wb_) = hh_; \
        *(unsigned short*)(lds + PLANE(L, 1) + wb_) = hl_; \
    } } while (0)

#define MLP1_(SLOT) do { \
    float b1_ = *(const float*)(lds + B1L_OFF + (hf * 16 + l15) * 4); \
    f32x4 a1_ = {b1_, b1_, b1_, b1_}; \
    _Pragma("unroll") for (int ks_ = 0; ks_ < 2; ++ks_) { \
        int ab_ = (((EB1 + l15) * 128 + ks_ * 64 + l4 * 16)) ^ rswz; \
        bf16x8 ah_ = *(const bf16x8*)(lds + PLANE(2, 0) + ab_); \
        bf16x8 al_ = *(const bf16x8*)(lds + PLANE(2, 1) + ab_); \
        bf16x8 wh_ = *(const bf16x8*)(lds + QB(SLOT) + (hf * 4 + ks_ * 2 + 0) * 1024 + lane * 16); \
        bf16x8 wl_ = *(const bf16x8*)(lds + QB(SLOT) + (hf * 4 + ks_ * 2 + 1) * 1024 + lane * 16); \
        a1_ = MFMA_(ah_, wh_, a1_); \
        a1_ = MFMA_(al_, wh_, a1_); \
        a1_ = MFMA_(ah_, wl_, a1_); \
    } \
    _Pragma("unroll") for (int r_ = 0; r_ < 4; ++r_) { \
        float y_ = a1_[r_]; y_ = (y_ >= 0.f) ? y_ : 0.01f * y_; \
        int e_ = EB1 + l4 * 4 + r_; \
        *(unsigned short*)(lds + Y1_OFF + e_ * 68 + hf * 32 + l15 * 2) = f2bf(y_); \
    } } while (0)

#define MLP2_ do { \
    int e2_ = hbase + (tih & 63), rg_ = tih >> 6; \
    float a2_[2]; \
    a2_[0] = *(const float*)(lds + B2L_OFF + (rg_ * 2 + 0) * 4); \
    a2_[1] = *(const float*)(lds + B2L_OFF + (rg_ * 2 + 1) * 4); \
    _Pragma("unroll") for (int kd_ = 0; kd_ < 16; ++kd_) { \
        unsigned int d_ = *(const unsigned int*)(lds + Y1_OFF + e2_ * 68 + kd_ * 4); \
        float v0_ = bf2f_lo(d_), v1_ = bf2f_hi(d_); \
        _Pragma("unroll") for (int m_ = 0; m_ < 2; ++m_) { \
            unsigned int w_ = *(const unsigned int*)(lds + W2L_OFF + ((rg_ * 2 + m_) * 32 + kd_ * 2) * 2); \
            a2_[m_] = fmaf(v0_, bf2f_lo(w_), a2_[m_]); \
            a2_[m_] = fmaf(v1_, bf2f_hi(w_), a2_[m_]); \
        } } \
    _Pragma("unroll") for (int m_ = 0; m_ < 2; ++m_) { \
        float y_ = a2_[m_]; y_ = (y_ >= 0.f) ? y_ : 0.01f * y_; \
        *(unsigned short*)(lds + Y2_OFF + e2_ * 36 + (rg_ * 2 + m_) * 2) = f2bf(y_); \
    } } while (0)

#define MLP3_ do { \
    if (tih < 192) { \
        int e3_ = hbase + (tih & 63), r3_ = tih >> 6; \
        float a3_ = *(const float*)(lds + B3L_OFF + r3_ * 4); \
        _Pragma("unroll") for (int kd_ = 0; kd_ < 8; ++kd_) { \
            unsigned int d_ = *(const unsigned int*)(lds + Y2_OFF + e3_ * 36 + kd_ * 4); \
            a3_ = fmaf(bf2f_lo(d_), *(const float*)(lds + W3L_OFF + (r3_ * 16 + kd_ * 2) * 4),     a3_); \
            a3_ = fmaf(bf2f_hi(d_), *(const float*)(lds + W3L_OFF + (r3_ * 16 + kd_ * 2 + 1) * 4), a3_); \
        } \
        float y_ = (a3_ >= 0.f) ? a3_ : 0.01f * a3_; \
        *(float*)(lds + XFB_OFF + e3_ * 12 + r3_ * 4) = y_; \
        *(float*)(lds + OUT_OFF + e3_ * 48 + (t & 3) * 12 + r3_ * 4) = y_; \
    } } while (0)

#define BAR __syncthreads()

// ---------------- main persistent kernel ----------------
extern "C" __global__ void __launch_bounds__(NTHR, 4)
lstm_mfma(const float* __restrict__ noise,
          const float* __restrict__ wih0, const float* __restrict__ whh0,
          const float* __restrict__ bih0, const float* __restrict__ bhh0,
          const float* __restrict__ wih1, const float* __restrict__ whh1,
          const float* __restrict__ bih1, const float* __restrict__ bhh1,
          const float* __restrict__ wih2, const float* __restrict__ whh2,
          const float* __restrict__ bih2, const float* __restrict__ bhh2,
          const float* __restrict__ w1g, const float* __restrict__ b1g,
          const float* __restrict__ w2g, const float* __restrict__ b2g,
          const float* __restrict__ w3g, const float* __restrict__ b3g,
          const int* __restrict__ lenp, float* __restrict__ out)
{
    extern __shared__ unsigned char lds[];
    const int tid  = threadIdx.x;
    const int lane = tid & 63;
    const int wv   = tid >> 6;          // wave 0..15
    const bool hA  = (wv < 8);          // half A = waves 0-7 (elems 0-63)
    const int wl   = wv & 7;            // wave-in-half
    const int ug   = wl & 3;            // unit group (16 units)
    const int mh   = wl >> 2;           // M half within the batch-half
    const int l15  = lane & 15;
    const int l4   = lane >> 4;
    const int u    = ug * 16 + l15;     // unit 0..63
    const int hbase = hA ? 0 : 64;
    const int mbase = hbase + mh * 32;
    const int rswz  = (lane & 7) << 4;
    const int hf    = wl & 1;           // MLP1 col-half
    const int Mt    = wl >> 1;          // MLP1 M-tile (0..3)
    const int EB1   = hbase + Mt * 16;
    const int tih   = tid & 511;        // thread-in-half
    const int T = *lenp;
    const long eg0  = (long)blockIdx.x * BT;
    const long outs = 3L * T;

    // per-thread recurrent c state: 8 units per layer
    float c0[8], c1[8], c2[8];
    #pragma unroll
    for (int i = 0; i < 8; ++i) { c0[i] = 0.f; c1[i] = 0.f; c2[i] = 0.f; }

    bf16x8 R;                 // pending staging register
    bf16x8 ahk0 = {}, ahk1 = {};  // A-fragment carry (GHI -> GLO)

    // warmup: load Q0 early
    R = *(const bf16x8*)(g_wsbuf + ((tid >> 6) * 4) * 1024 + (tid & 63) * 16);

    // ---- LDS init ----
    for (int i = tid; i < 98304 / 4; i += NTHR) ((unsigned int*)lds)[i] = 0u;  // h planes = 0
    if (tid < BT) {
        #pragma unroll
        for (int k = 0; k < 3; ++k)
            *(float*)(lds + XFB_OFF + tid * 12 + k * 4) = noise[(eg0 + tid) * 3 + k];
    }
    if (tid < 512) *(unsigned short*)(lds + W2L_OFF + tid * 2) = f2bf(w2g[tid]);
    if (tid < 768) {                                   // bias sums, log2e-scaled
        int l = tid >> 8, r = tid & 255, g = (r >> 6);
        float fac = (g == 2) ? (2.0f * L2E) : L2E;
        const float* bi = (l == 0) ? bih0 : ((l == 1) ? bih1 : bih2);
        const float* bh = (l == 0) ? bhh0 : ((l == 1) ? bhh1 : bhh2);
        *(float*)(lds + BGL_OFF + tid * 4) = (bi[r] + bh[r]) * fac;
    }
    if (tid < 768) {                                   // wih0, log2e-scaled
        int r = tid / 3, g = r >> 6;
        float fac = (g == 2) ? (2.0f * L2E) : L2E;
        *(float*)(lds + W0L_OFF + tid * 4) = wih0[tid] * fac;
    }
    if (tid < 32) *(float*)(lds + B1L_OFF + tid * 4) = b1g[tid];
    if (tid < 16) *(float*)(lds + B2L_OFF + tid * 4) = b2g[tid];
    if (tid < 3)  *(float*)(lds + B3L_OFF + tid * 4) = b3g[tid];
    if (tid < 48) *(float*)(lds + W3L_OFF + tid * 4) = w3g[tid];

    BAR;
    // commit Q0 -> slot0; load Q1 (lo-ks0)
    CL(0, 0, 0, 1);
    BAR;

    f32x4 acc[4][2];

    // Quarter order per matrix: [hi-ks0, lo-ks0, hi-ks1, lo-ks1]
    // Half-B executes half-A's program shifted +1 phase.
    #pragma unroll 1
    for (int t = 0; t < T; ++t) {
        /*k0*/  CL(1, 0, 1, 0);
                if (hA) { ACC_(0); XPART_; GHI_(0, 0, 0); }
                BAR;
        /*k1*/  CL(2, 0, 1, 1);
                if (hA) { GLO_(1); } else { ACC_(0); XPART_; GHI_(0, 0, 0); }
                BAR;
        /*k2*/  CL(0, 1, 0, 0);
                if (hA) { GHI_(0, 1, 2); } else { GLO_(1); }
                BAR;
        /*k3*/  if (hA) { GLO_(0); } else { GHI_(0, 1, 2); }
                BAR;
        /*k4*/  CL(1, 1, 0, 1);
                if (hA) { CELL_(0, c0); } else { GLO_(0); }
                BAR;
        /*k5*/  CL(2, 1, 1, 0);
                if (hA) { ACC_(1); GHI_(0, 0, 1); } else { CELL_(0, c0); }
                BAR;
        /*k6*/  CL(0, 1, 1, 1);
                if (hA) { GLO_(2); } else { ACC_(1); GHI_(0, 0, 1); }
                BAR;
        /*k7*/  CL(1, 2, 0, 0);
                if (hA) { GHI_(0, 1, 0); } else { GLO_(2); }
                BAR;
        /*k8*/  CL(2, 2, 0, 1);
                if (hA) { GLO_(1); } else { GHI_(0, 1, 0); }
                BAR;
        /*k9*/  CL(0, 2, 1, 0);
                if (hA) { GHI_(1, 0, 2); } else { GLO_(1); }
                BAR;
        /*k10*/ CL(1, 2, 1, 1);
                if (hA) { GLO_(0); } else { GHI_(1, 0, 2); }
                BAR;
        /*k11*/ CL(2, 3, 0, 0);
                if (hA) { GHI_(1, 1, 1); } else { GLO_(0); }
                BAR;
        /*k12*/ if (hA) { GLO_(2); } else { GHI_(1, 1, 1); }
                BAR;
        /*k13*/ CL(0, 3, 0, 1);
                if (hA) { CELL_(1, c1); } else { GLO_(2); }
                BAR;
        /*k14*/ CL(1, 3, 1, 0);
                if (hA) { ACC_(2); GHI_(1, 0, 0); } else { CELL_(1, c1); }
                BAR;
        /*k15*/ CL(2, 3, 1, 1);
                if (hA) { GLO_(1); } else { ACC_(2); GHI_(1, 0, 0); }
                BAR;
        /*k16*/ CL(0, 4, 0, 0);
                if (hA) { GHI_(1, 1, 2); } else { GLO_(1); }
                BAR;
        /*k17*/ CL(1, 4, 0, 1);
                if (hA) { GLO_(0); } else { GHI_(1, 1, 2); }
                BAR;
        /*k18*/ CL(2, 4, 1, 0);
                if (hA) { GHI_(2, 0, 1); } else { GLO_(0); }
                BAR;
        /*k19*/ CL(0, 4, 1, 1);
                if (hA) { GLO_(2); } else { GHI_(2, 0, 1); }
                BAR;
        /*k20*/ CLW1(1);
                if (hA) { GHI_(2, 1, 0); } else { GLO_(2); }
                BAR;
        /*k21*/ if (hA) { GLO_(1); } else { GHI_(2, 1, 0); }
                BAR;
        /*k22*/ CL(2, 0, 0, 0);
                if (hA) { CELL_(2, c2); } else { GLO_(1); }
                BAR;
        /*k23*/ if (hA) { MLP1_(2); } else { CELL_(2, c2); }
                BAR;
        /*k24*/ if (hA) { MLP2_; } else { MLP1_(2); }
                BAR;
        /*k25*/ if (hA) { MLP3_; } else { MLP2_; }
                BAR;
        /*k26*/ CL(0, 0, 0, 1);
                if (!hA) { MLP3_; }
                BAR;
        if ((t & 3) == 3) {                     // flush 4 buffered steps
            long tb = t - 3;
            #pragma unroll
            for (int it = 0; it < 2; ++it) {
                int i = it * NTHR + tid;
                if (i < 1536) {
                    int e = i / 12, rem = i - e * 12;
                    int st = rem / 3, j = rem - st * 3;
                    out[(eg0 + e) * outs + (tb + st) * 3 + j] =
                        *(const float*)(lds + OUT_OFF + e * 48 + st * 12 + j * 4);
                }
            }
            BAR;
        }
    }

    // tail flush (T not multiple of 4)
    int nst = T & 3;
    if (nst) {
        int nfl = BT * nst * 3;
        for (int i = tid; i < nfl; i += NTHR) {
            int e = i / (nst * 3), rem = i - e * (nst * 3);
            int st = rem / 3, j = rem - st * 3;
            out[(eg0 + e) * outs + (long)(T - nst + st) * 3 + j] =
                *(const float*)(lds + OUT_OFF + e * 48 + st * 12 + j * 4);
        }
    }
}

extern "C" void kernel_launch(void* const* d_in, const int* in_sizes, int n_in,
                              void* d_out, int out_size, void* d_ws, size_t ws_size,
                              hipStream_t stream)
{
    const float* noise = (const float*)d_in[0];
    const float* wih0  = (const float*)d_in[1];
    const float* whh0  = (const float*)d_in[2];
    const float* bih0  = (const float*)d_in[3];
    const float* bhh0  = (const float*)d_in[4];
    const float* wih1  = (const float*)d_in[5];
    const float* whh1  = (const float*)d_in[6];
    const float* bih1  = (const float*)d_in[7];
    const float* bhh1  = (const float*)d_in[8];
    const float* wih2  = (const float*)d_in[9];
    const float* whh2  = (const float*)d_in[10];
    const float* bih2  = (const float*)d_in[11];
    const float* bhh2  = (const float*)d_in[12];
    const float* w1g   = (const float*)d_in[13];
    const float* b1g   = (const float*)d_in[14];
    const float* w2g   = (const float*)d_in[15];
    const float* b2g   = (const float*)d_in[16];
    const float* w3g   = (const float*)d_in[17];
    const float* b3g   = (const float*)d_in[18];
    const int*   lenp  = (const int*)d_in[19];
    float* out = (float*)d_out;

    int B = in_sizes[0] / 3;              // 32768
    int grid = B / BT;                    // 256 blocks = 1 per CU

    prep_weights<<<82, 256, 0, stream>>>(whh0, wih1, whh1, wih2, whh2, w1g);

    hipFuncSetAttribute((const void*)lstm_mfma,
                        hipFuncAttributeMaxDynamicSharedMemorySize, LDS_TOTAL);
    lstm_mfma<<<grid, NTHR, LDS_TOTAL, stream>>>(
        noise, wih0, whh0, bih0, bhh0, wih1, whh1, bih1, bhh1,
        wih2, whh2, bih2, bhh2, w1g, b1g, w2g, b2g, w3g, b3g, lenp, out);
}

// Round 7
// 5857.050 us; speedup vs baseline: 2.3954x; 1.6335x over previous
//
#include <hip/hip_runtime.h>

typedef __attribute__((ext_vector_type(4))) float  f32x4;
typedef __attribute__((ext_vector_type(8))) short  bf16x8;

#define NTHR 1024
#define BT   128
#define L2E  1.4426950408889634f

// ---------------- LDS byte map (total 159632 <= 163840) ----------------
// planes: [layer][split] 16384B each: [128 elems][64 units] bf16, XOR-swizzled
#define PLANE(L,S) ((L)*32768 + (S)*16384)
#define QBUFP(p)   (98304 + ((p)<<14))     // 2 parity-rotating 16KB stage buffers
#define XFB_OFF    131072                  // [128][3] f32 feedback x (1536B)
#define Y1_OFF     132608                  // [128][34] bf16 (8704B)
#define Y2_OFF     141312                  // [128][18] bf16 (4608B)
#define W2L_OFF    145920                  // [16][32] bf16 (1024B)
#define BGL_OFF    146944                  // [3][256] f32 bias sums, log2e-scaled (3072B)
#define B1L_OFF    150016                  // [32] f32
#define B2L_OFF    150144                  // [16] f32
#define B3L_OFF    150208                  // [4] f32
#define W3L_OFF    150224                  // [3][16] f32 (192B)
#define W0L_OFF    150416                  // [256][3] f32, log2e-scaled (3072B)
#define OUT_OFF    153488                  // [128][12] f32 out ring, 4 steps (6144B)
#define LDS_TOTAL  159632

// frag-ordered split weights (gate mats log2e-prescaled): 5 mats * 64KB + w1 8KB
__device__ __align__(16) unsigned char g_wsbuf[335872];

__device__ __forceinline__ unsigned short f2bf(float v) {
    unsigned int x = __float_as_uint(v);
    unsigned int r = x + 0x7fffu + ((x >> 16) & 1u);
    return (unsigned short)(r >> 16);
}
__device__ __forceinline__ float bf2f_lo(unsigned int d) { return __uint_as_float(d << 16); }
__device__ __forceinline__ float bf2f_hi(unsigned int d) { return __uint_as_float(d & 0xffff0000u); }

// gates pre-scaled by log2e (2*log2e for g-gate): pure exp2 forms
__device__ __forceinline__ float fsig2(float y) {   // sigmoid(x), y = x*log2e
    return __builtin_amdgcn_rcpf(1.0f + __builtin_amdgcn_exp2f(-y));
}
__device__ __forceinline__ float ftanh2(float y) {  // tanh(x), y = 2x*log2e
    return 1.0f - 2.0f * __builtin_amdgcn_rcpf(1.0f + __builtin_amdgcn_exp2f(y));
}
__device__ __forceinline__ float ftanhc(float c) {  // tanh(c), c true-scale
    return 1.0f - 2.0f * __builtin_amdgcn_rcpf(1.0f + __builtin_amdgcn_exp2f(c * (2.0f * L2E)));
}

// ---------------- prologue: frag-order + split + log2e prescale ----------------
__global__ void prep_weights(const float* __restrict__ whh0, const float* __restrict__ wih1,
                             const float* __restrict__ whh1, const float* __restrict__ wih2,
                             const float* __restrict__ whh2, const float* __restrict__ w1g)
{
    int gi = blockIdx.x * 256 + threadIdx.x;
    if (gi < 20480) {
        int m = gi >> 12;
        int rem = gi & 4095;
        int b = rem >> 6, l = rem & 63;
        int s = b & 1, ks = (b >> 1) & 1, g = (b >> 2) & 3, ug = b >> 4;
        int row = g * 64 + ug * 16 + (l & 15);
        int kb  = ks * 32 + (l >> 4) * 8;
        float fac = (g == 2) ? (2.0f * L2E) : L2E;
        const float* src = (m == 0) ? whh0 : (m == 1) ? wih1 : (m == 2) ? whh1
                         : (m == 3) ? wih2 : whh2;
        unsigned short o[8];
        #pragma unroll
        for (int i = 0; i < 8; ++i) {
            float v = src[row * 64 + kb + i] * fac;
            unsigned short hh = f2bf(v);
            if (s) {
                float r2 = v - __uint_as_float((unsigned int)hh << 16);
                hh = f2bf(r2);
            }
            o[i] = hh;
        }
        unsigned char* dst = g_wsbuf + m * 65536 + b * 1024 + l * 16;
        #pragma unroll
        for (int i = 0; i < 8; ++i) ((unsigned short*)dst)[i] = o[i];
    } else if (gi < 20992) {
        int g2 = gi - 20480;
        int b = g2 >> 6, l = g2 & 63;
        int s = b & 1, ks = (b >> 1) & 1, nt = b >> 2;
        int row = nt * 16 + (l & 15);
        int kb  = ks * 32 + (l >> 4) * 8;
        unsigned short o[8];
        #pragma unroll
        for (int i = 0; i < 8; ++i) {
            float v = w1g[row * 64 + kb + i];           // w1: unscaled
            unsigned short hh = f2bf(v);
            if (s) {
                float r2 = v - __uint_as_float((unsigned int)hh << 16);
                hh = f2bf(r2);
            }
            o[i] = hh;
        }
        unsigned char* dst = g_wsbuf + 327680 + b * 1024 + l * 16;
        #pragma unroll
        for (int i = 0; i < 8; ++i) ((unsigned short*)dst)[i] = o[i];
    }
}

#define MFMA_(A,B,C) __builtin_amdgcn_mfma_f32_16x16x32_bf16(A, B, C, 0, 0, 0)

// 1024-thread staging: one dwordx4 per thread per 16KB quarter.
#define LOADQ(m, ks, s, R) \
    R = *(const bf16x8*)(g_wsbuf + (m) * 65536 + \
        (((tid >> 6) * 4 + (ks) * 2 + (s))) * 1024 + (tid & 63) * 16)
#define COMMITQ(R, p) \
    *(bf16x8*)(lds + QBUFP(p) + tid * 16) = R
#define LOADW1(R) do { if (tid < 512) \
    R = *(const bf16x8*)(g_wsbuf + 327680 + (tid >> 6) * 1024 + (tid & 63) * 16); } while (0)
#define COMMITW1(R, p) do { if (tid < 512) \
    *(bf16x8*)(lds + QBUFP(p) + tid * 16) = R; } while (0)

#define ACC_INIT(L) do { \
    _Pragma("unroll") for (int g_ = 0; g_ < 4; ++g_) { \
        float b_ = *(const float*)(lds + BGL_OFF + ((L) * 256 + g_ * 64 + u) * 4); \
        f32x4 t_ = {b_, b_, b_, b_}; \
        _Pragma("unroll") for (int mt_ = 0; mt_ < 2; ++mt_) acc[g_][mt_] = t_; \
    } } while (0)

#define GATE_HI(APL, ks, P) do { \
    bf16x8 bh_[4]; \
    _Pragma("unroll") for (int g_ = 0; g_ < 4; ++g_) \
        bh_[g_] = *(const bf16x8*)(lds + QBUFP(P) + (ug * 4 + g_) * 1024 + lane * 16); \
    _Pragma("unroll") for (int mt_ = 0; mt_ < 2; ++mt_) { \
        int ab_ = (((mbase + mt_ * 16 + l15) * 128 + (ks) * 64 + l4 * 16)) ^ rswz; \
        bf16x8 ah_ = *(const bf16x8*)(lds + PLANE(APL, 0) + ab_); \
        bf16x8 al_ = *(const bf16x8*)(lds + PLANE(APL, 1) + ab_); \
        _Pragma("unroll") for (int g_ = 0; g_ < 4; ++g_) { \
            acc[g_][mt_] = MFMA_(ah_, bh_[g_], acc[g_][mt_]); \
            acc[g_][mt_] = MFMA_(al_, bh_[g_], acc[g_][mt_]); \
        } } } while (0)

#define GATE_LO(APL, ks, P) do { \
    bf16x8 bl_[4]; \
    _Pragma("unroll") for (int g_ = 0; g_ < 4; ++g_) \
        bl_[g_] = *(const bf16x8*)(lds + QBUFP(P) + (ug * 4 + g_) * 1024 + lane * 16); \
    _Pragma("unroll") for (int mt_ = 0; mt_ < 2; ++mt_) { \
        int ab_ = (((mbase + mt_ * 16 + l15) * 128 + (ks) * 64 + l4 * 16)) ^ rswz; \
        bf16x8 ah_ = *(const bf16x8*)(lds + PLANE(APL, 0) + ab_); \
        _Pragma("unroll") for (int g_ = 0; g_ < 4; ++g_) \
            acc[g_][mt_] = MFMA_(ah_, bl_[g_], acc[g_][mt_]); \
    } } while (0)

#define CELLW(L, CARR) do { \
    _Pragma("unroll") for (int mt_ = 0; mt_ < 2; ++mt_) \
    _Pragma("unroll") for (int r_ = 0; r_ < 4; ++r_) { \
        float gi_ = fsig2(acc[0][mt_][r_]); \
        float gf_ = fsig2(acc[1][mt_][r_]); \
        float gg_ = ftanh2(acc[2][mt_][r_]); \
        float go_ = fsig2(acc[3][mt_][r_]); \
        float cn_ = gf_ * CARR[mt_ * 4 + r_] + gi_ * gg_; \
        CARR[mt_ * 4 + r_] = cn_; \
        float hn_ = go_ * ftanhc(cn_); \
        int e_ = mbase + mt_ * 16 + l4 * 4 + r_; \
        int wb_ = ((e_ * 128 + u * 2)) ^ ((e_ & 7) << 4); \
        unsigned short hh_ = f2bf(hn_); \
        float hf2_ = __uint_as_float((unsigned int)hh_ << 16); \
        unsigned short hl_ = f2bf(hn_ - hf2_); \
        *(unsigned short*)(lds + PLANE(L, 0) + wb_) = hh_; \
        *(unsigned short*)(lds + PLANE(L, 1) + wb_) = hl_; \
    } } while (0)

#define XPART do { \
    _Pragma("unroll") for (int mt_ = 0; mt_ < 2; ++mt_) \
    _Pragma("unroll") for (int r_ = 0; r_ < 4; ++r_) { \
        int e_ = mbase + mt_ * 16 + l4 * 4 + r_; \
        const float* xp_ = (const float*)(lds + XFB_OFF + e_ * 12); \
        float x0_ = xp_[0], x1_ = xp_[1], x2_ = xp_[2]; \
        _Pragma("unroll") for (int g_ = 0; g_ < 4; ++g_) { \
            const float* w0_ = (const float*)(lds + W0L_OFF + (g_ * 64 + u) * 12); \
            acc[g_][mt_][r_] += x0_ * w0_[0] + x1_ * w0_[1] + x2_ * w0_[2]; \
        } } } while (0)

#define MLP1(P) do { \
    int Mt_ = wv >> 1, half_ = wv & 1; \
    float b1_ = *(const float*)(lds + B1L_OFF + (half_ * 16 + l15) * 4); \
    f32x4 a1_ = {b1_, b1_, b1_, b1_}; \
    _Pragma("unroll") for (int ks_ = 0; ks_ < 2; ++ks_) { \
        int ab_ = (((Mt_ * 16 + l15) * 128 + ks_ * 64 + l4 * 16)) ^ rswz; \
        bf16x8 ah_ = *(const bf16x8*)(lds + PLANE(2, 0) + ab_); \
        bf16x8 al_ = *(const bf16x8*)(lds + PLANE(2, 1) + ab_); \
        bf16x8 wh_ = *(const bf16x8*)(lds + QBUFP(P) + ((half_ * 2 + ks_) * 2 + 0) * 1024 + lane * 16); \
        bf16x8 wl_ = *(const bf16x8*)(lds + QBUFP(P) + ((half_ * 2 + ks_) * 2 + 1) * 1024 + lane * 16); \
        a1_ = MFMA_(ah_, wh_, a1_); \
        a1_ = MFMA_(al_, wh_, a1_); \
        a1_ = MFMA_(ah_, wl_, a1_); \
    } \
    _Pragma("unroll") for (int r_ = 0; r_ < 4; ++r_) { \
        float y_ = a1_[r_]; y_ = (y_ >= 0.f) ? y_ : 0.01f * y_; \
        int e_ = Mt_ * 16 + l4 * 4 + r_; \
        *(unsigned short*)(lds + Y1_OFF + e_ * 68 + half_ * 32 + l15 * 2) = f2bf(y_); \
    } } while (0)

#define MLP2 do { \
    int e2_ = tid & 127, rg_ = tid >> 7; \
    float a2_[2]; \
    _Pragma("unroll") for (int m_ = 0; m_ < 2; ++m_) \
        a2_[m_] = *(const float*)(lds + B2L_OFF + (rg_ * 2 + m_) * 4); \
    _Pragma("unroll") for (int kd_ = 0; kd_ < 16; ++kd_) { \
        unsigned int d_ = *(const unsigned int*)(lds + Y1_OFF + e2_ * 68 + kd_ * 4); \
        float v0_ = bf2f_lo(d_), v1_ = bf2f_hi(d_); \
        _Pragma("unroll") for (int m_ = 0; m_ < 2; ++m_) { \
            unsigned int w_ = *(const unsigned int*)(lds + W2L_OFF + ((rg_ * 2 + m_) * 32 + kd_ * 2) * 2); \
            a2_[m_] = fmaf(v0_, bf2f_lo(w_), a2_[m_]); \
            a2_[m_] = fmaf(v1_, bf2f_hi(w_), a2_[m_]); \
        } } \
    _Pragma("unroll") for (int m_ = 0; m_ < 2; ++m_) { \
        float y_ = a2_[m_]; y_ = (y_ >= 0.f) ? y_ : 0.01f * y_; \
        *(unsigned short*)(lds + Y2_OFF + e2_ * 36 + (rg_ * 2 + m_) * 2) = f2bf(y_); \
    } } while (0)

#define MLP3_OUT do { \
    if (tid < 384) { \
        int e3_ = tid & 127, r3_ = tid >> 7; \
        float a3_ = *(const float*)(lds + B3L_OFF + r3_ * 4); \
        _Pragma("unroll") for (int kd_ = 0; kd_ < 8; ++kd_) { \
            unsigned int d_ = *(const unsigned int*)(lds + Y2_OFF + e3_ * 36 + kd_ * 4); \
            a3_ = fmaf(bf2f_lo(d_), *(const float*)(lds + W3L_OFF + (r3_ * 16 + kd_ * 2) * 4),     a3_); \
            a3_ = fmaf(bf2f_hi(d_), *(const float*)(lds + W3L_OFF + (r3_ * 16 + kd_ * 2 + 1) * 4), a3_); \
        } \
        float y_ = (a3_ >= 0.f) ? a3_ : 0.01f * a3_; \
        *(float*)(lds + XFB_OFF + e3_ * 12 + r3_ * 4) = y_; \
        *(float*)(lds + OUT_OFF + e3_ * 48 + (t & 3) * 12 + r3_ * 4) = y_; \
    } } while (0)

// ---------------- main persistent kernel ----------------
extern "C" __global__ void __launch_bounds__(NTHR)
__attribute__((amdgpu_waves_per_eu(4, 4)))
lstm_mfma(const float* __restrict__ noise,
          const float* __restrict__ wih0, const float* __restrict__ whh0,
          const float* __restrict__ bih0, const float* __restrict__ bhh0,
          const float* __restrict__ wih1, const float* __restrict__ whh1,
          const float* __restrict__ bih1, const float* __restrict__ bhh1,
          const float* __restrict__ wih2, const float* __restrict__ whh2,
          const float* __restrict__ bih2, const float* __restrict__ bhh2,
          const float* __restrict__ w1g, const float* __restrict__ b1g,
          const float* __restrict__ w2g, const float* __restrict__ b2g,
          const float* __restrict__ w3g, const float* __restrict__ b3g,
          const int* __restrict__ lenp, float* __restrict__ out)
{
    extern __shared__ unsigned char lds[];
    const int tid  = threadIdx.x;
    const int lane = tid & 63;
    const int wv   = tid >> 6;       // wave 0..15
    const int ug   = wv & 3;         // unit group (16 units)
    const int mh   = wv >> 2;        // M quarter 0..3
    const int l15  = lane & 15;
    const int l4   = lane >> 4;      // k-group
    const int u    = ug * 16 + l15;  // unit 0..63
    const int mbase = mh * 32;
    const int rswz  = (lane & 7) << 4;
    const int T = *lenp;
    const long eg0  = (long)blockIdx.x * BT;
    const long outs = 3L * T;

    // per-thread recurrent c state: 8 (unit,elem) pairs per layer
    float c0[8], c1[8], c2[8];
    #pragma unroll
    for (int i = 0; i < 8; ++i) { c0[i] = 0.f; c1[i] = 0.f; c2[i] = 0.f; }

    // staging registers (3-deep rotation)
    bf16x8 RA, RB, RC;

    // issue warmup loads early (q0,q1,q2)
    LOADQ(0, 0, 0, RA);
    LOADQ(0, 1, 0, RB);
    LOADQ(0, 0, 1, RC);

    // ---- LDS init ----
    for (int i = tid; i < 98304 / 4; i += NTHR) ((unsigned int*)lds)[i] = 0u;  // h planes = 0
    if (tid < BT) {
        #pragma unroll
        for (int k = 0; k < 3; ++k)
            *(float*)(lds + XFB_OFF + tid * 12 + k * 4) = noise[(eg0 + tid) * 3 + k];
    }
    if (tid < 512) *(unsigned short*)(lds + W2L_OFF + tid * 2) = f2bf(w2g[tid]);
    if (tid < 768) {                                   // bias sums, log2e-scaled
        int l = tid >> 8, r = tid & 255, g = r >> 6;
        float fac = (g == 2) ? (2.0f * L2E) : L2E;
        const float* bi = (l == 0) ? bih0 : ((l == 1) ? bih1 : bih2);
        const float* bh = (l == 0) ? bhh0 : ((l == 1) ? bhh1 : bhh2);
        *(float*)(lds + BGL_OFF + tid * 4) = (bi[r] + bh[r]) * fac;
    }
    if (tid < 768) {                                   // wih0, log2e-scaled
        int r = tid / 3, g = r >> 6;
        float fac = (g == 2) ? (2.0f * L2E) : L2E;
        *(float*)(lds + W0L_OFF + tid * 4) = wih0[tid] * fac;
    }
    if (tid < 32) *(float*)(lds + B1L_OFF + tid * 4) = b1g[tid];
    if (tid < 16) *(float*)(lds + B2L_OFF + tid * 4) = b2g[tid];
    if (tid < 3)  *(float*)(lds + B3L_OFF + tid * 4) = b3g[tid];
    if (tid < 48) *(float*)(lds + W3L_OFF + tid * 4) = w3g[tid];

    __syncthreads();                 // init visible
    COMMITQ(RA, 0);                  // q0 -> buf0 (vmcnt auto-waited)
    __syncthreads();                 // buf0 ready

    f32x4 acc[4][2];

    #pragma unroll 1
    for (int t = 0; t < T; ++t) {
        const int bp = t & 1;
        // ---------------- layer 0: whh0 q0..q3 (A = plane0 old) ----------------
        COMMITQ(RB, bp ^ 1); LOADQ(0, 1, 1, RA);      // commit q1, load q3
        ACC_INIT(0); XPART;
        GATE_HI(0, 0, bp);                            // q0
        __syncthreads();
        COMMITQ(RC, bp); LOADQ(1, 0, 0, RB);          // commit q2, load q4
        GATE_HI(0, 1, bp ^ 1);                        // q1
        __syncthreads();
        COMMITQ(RA, bp ^ 1); LOADQ(1, 1, 0, RC);      // commit q3, load q5
        GATE_LO(0, 0, bp);                            // q2
        __syncthreads();
        COMMITQ(RB, bp); LOADQ(1, 0, 1, RA);          // commit q4, load q6
        GATE_LO(0, 1, bp ^ 1);                        // q3
        __syncthreads();
        CELLW(0, c0);                                 // h0 -> plane0
        __syncthreads();
        // ---------------- layer 1: wih1 q4..q7 (A=plane0 new), whh1 q8..q11 (A=plane1 old) ----------------
        ACC_INIT(1);
        COMMITQ(RC, bp ^ 1); LOADQ(1, 1, 1, RB);      // commit q5, load q7
        GATE_HI(0, 0, bp);                            // q4
        __syncthreads();
        COMMITQ(RA, bp); LOADQ(2, 0, 0, RC);          // commit q6, load q8
        GATE_HI(0, 1, bp ^ 1);                        // q5
        __syncthreads();
        COMMITQ(RB, bp ^ 1); LOADQ(2, 1, 0, RA);      // commit q7, load q9
        GATE_LO(0, 0, bp);                            // q6
        __syncthreads();
        COMMITQ(RC, bp); LOADQ(2, 0, 1, RB);          // commit q8, load q10
        GATE_LO(0, 1, bp ^ 1);                        // q7
        __syncthreads();
        COMMITQ(RA, bp ^ 1); LOADQ(2, 1, 1, RC);      // commit q9, load q11
        GATE_HI(1, 0, bp);                            // q8
        __syncthreads();
        COMMITQ(RB, bp); LOADQ(3, 0, 0, RA);          // commit q10, load q12
        GATE_HI(1, 1, bp ^ 1);                        // q9
        __syncthreads();
        COMMITQ(RC, bp ^ 1); LOADQ(3, 1, 0, RB);      // commit q11, load q13
        GATE_LO(1, 0, bp);                            // q10
        __syncthreads();
        COMMITQ(RA, bp); LOADQ(3, 0, 1, RC);          // commit q12, load q14
        GATE_LO(1, 1, bp ^ 1);                        // q11
        __syncthreads();
        CELLW(1, c1);                                 // h1 -> plane1
        __syncthreads();
        // ---------------- layer 2: wih2 q12..q15 (A=plane1 new), whh2 q16..q19 (A=plane2 old) ----------------
        ACC_INIT(2);
        COMMITQ(RB, bp ^ 1); LOADQ(3, 1, 1, RA);      // commit q13, load q15
        GATE_HI(1, 0, bp);                            // q12
        __syncthreads();
        COMMITQ(RC, bp); LOADQ(4, 0, 0, RB);          // commit q14, load q16
        GATE_HI(1, 1, bp ^ 1);                        // q13
        __syncthreads();
        COMMITQ(RA, bp ^ 1); LOADQ(4, 1, 0, RC);      // commit q15, load q17
        GATE_LO(1, 0, bp);                            // q14
        __syncthreads();
        COMMITQ(RB, bp); LOADQ(4, 0, 1, RA);          // commit q16, load q18
        GATE_LO(1, 1, bp ^ 1);                        // q15
        __syncthreads();
        COMMITQ(RC, bp ^ 1); LOADQ(4, 1, 1, RB);      // commit q17, load q19
        GATE_HI(2, 0, bp);                            // q16
        __syncthreads();
        COMMITQ(RA, bp); LOADW1(RC);                  // commit q18, load q20 (w1)
        GATE_HI(2, 1, bp ^ 1);                        // q17
        __syncthreads();
        COMMITQ(RB, bp ^ 1); LOADQ(0, 0, 0, RA);      // commit q19, load q0'
        GATE_LO(2, 0, bp);                            // q18
        __syncthreads();
        COMMITW1(RC, bp); LOADQ(0, 1, 0, RB);         // commit q20(w1), load q1'
        GATE_LO(2, 1, bp ^ 1);                        // q19
        __syncthreads();
        CELLW(2, c2);                                 // h2 -> plane2
        __syncthreads();
        // ---------------- MLP head ----------------
        COMMITQ(RA, bp ^ 1); LOADQ(0, 0, 1, RC);      // commit q0', load q2'
        MLP1(bp);                                     // y1 via MFMA (A=plane2, B=w1)
        __syncthreads();
        MLP2;                                         // y1 -> y2 (VALU)
        __syncthreads();
        MLP3_OUT;                                     // y2 -> XFB + out ring
        if ((t & 3) == 3) {                           // flush 4 buffered steps
            __syncthreads();
            long tb = t - 3;
            #pragma unroll
            for (int it = 0; it < 2; ++it) {
                int i = it * NTHR + tid;
                if (i < 1536) {
                    int e = i / 12, j = i - e * 12;
                    out[(eg0 + e) * outs + tb * 3 + j] =
                        *(const float*)(lds + OUT_OFF + e * 48 + j * 4);
                }
            }
        }
        __syncthreads();                              // step boundary
    }

    // tail flush (T not multiple of 4)
    int nst = T & 3;
    if (nst) {
        int nfl = BT * nst * 3;
        for (int i = tid; i < nfl; i += NTHR) {
            int e = i / (nst * 3), j = i - e * (nst * 3);
            out[(eg0 + e) * outs + (long)(T - nst) * 3 + j] =
                *(const float*)(lds + OUT_OFF + e * 48 + j * 4);
        }
    }
}

extern "C" void kernel_launch(void* const* d_in, const int* in_sizes, int n_in,
                              void* d_out, int out_size, void* d_ws, size_t ws_size,
                              hipStream_t stream)
{
    const float* noise = (const float*)d_in[0];
    const float* wih0  = (const float*)d_in[1];
    const float* whh0  = (const float*)d_in[2];
    const float* bih0  = (const float*)d_in[3];
    const float* bhh0  = (const float*)d_in[4];
    const float* wih1  = (const float*)d_in[5];
    const float* whh1  = (const float*)d_in[6];
    const float* bih1  = (const float*)d_in[7];
    const float* bhh1  = (const float*)d_in[8];
    const float* wih2  = (const float*)d_in[9];
    const float* whh2  = (const float*)d_in[10];
    const float* bih2  = (const float*)d_in[11];
    const float* bhh2  = (const float*)d_in[12];
    const float* w1g   = (const float*)d_in[13];
    const float* b1g   = (const float*)d_in[14];
    const float* w2g   = (const float*)d_in[15];
    const float* b2g   = (const float*)d_in[16];
    const float* w3g   = (const float*)d_in[17];
    const float* b3g   = (const float*)d_in[18];
    const int*   lenp  = (const int*)d_in[19];
    float* out = (float*)d_out;

    int B = in_sizes[0] / 3;              // 32768
    int grid = B / BT;                    // 256 blocks = 1 per CU

    prep_weights<<<82, 256, 0, stream>>>(whh0, wih1, whh1, wih2, whh2, w1g);

    hipFuncSetAttribute((const void*)lstm_mfma,
                        hipFuncAttributeMaxDynamicSharedMemorySize, LDS_TOTAL);
    lstm_mfma<<<grid, NTHR, LDS_TOTAL, stream>>>(
        noise, wih0, whh0, bih0, bhh0, wih1, whh1, bih1, bhh1,
        wih2, whh2, bih2, bhh2, w1g, b1g, w2g, b2g, w3g, b3g, lenp, out);
}

// Round 8
// 5627.075 us; speedup vs baseline: 2.4933x; 1.0409x over previous
//
#include <hip/hip_runtime.h>

typedef __attribute__((ext_vector_type(4))) float  f32x4;
typedef __attribute__((ext_vector_type(8))) short  bf16x8;

#define NTHR 1024
#define BT   128
#define L2E  1.4426950408889634f

// ---------------- LDS byte map (total 159632 <= 163840) ----------------
// planes: [layer][split] 16384B each: [128 elems][64 units] bf16, XOR-swizzled
#define PLANE(L,S) ((L)*32768 + (S)*16384)
#define QBUFP(p)   (98304 + ((p)<<14))     // 2 parity-rotating 16KB stage buffers
#define XFB_OFF    131072                  // [128][3] f32 feedback x (1536B)
#define Y1_OFF     132608                  // [128][34] bf16 (8704B)
#define Y2_OFF     141312                  // [128][18] bf16 (4608B)
#define W2L_OFF    145920                  // [16][32] bf16 (1024B)
#define BGL_OFF    146944                  // [3][256] f32 bias sums, log2e-scaled (3072B)
#define B1L_OFF    150016                  // [32] f32
#define B2L_OFF    150144                  // [16] f32
#define B3L_OFF    150208                  // [4] f32
#define W3L_OFF    150224                  // [3][16] f32 (192B)
#define W0L_OFF    150416                  // [256][3] f32, log2e-scaled (3072B)
#define OUT_OFF    153488                  // [128][12] f32 out ring, 4 steps (6144B)
#define LDS_TOTAL  159632

// frag-ordered split weights (gate mats log2e-prescaled): 5 mats * 64KB + w1 8KB
__device__ __align__(16) unsigned char g_wsbuf[335872];

__device__ __forceinline__ unsigned short f2bf(float v) {
    unsigned int x = __float_as_uint(v);
    unsigned int r = x + 0x7fffu + ((x >> 16) & 1u);
    return (unsigned short)(r >> 16);
}
__device__ __forceinline__ float bf2f_lo(unsigned int d) { return __uint_as_float(d << 16); }
__device__ __forceinline__ float bf2f_hi(unsigned int d) { return __uint_as_float(d & 0xffff0000u); }

// gates pre-scaled by log2e (2*log2e for g-gate): pure exp2 forms
__device__ __forceinline__ float fsig2(float y) {   // sigmoid(x), y = x*log2e
    return __builtin_amdgcn_rcpf(1.0f + __builtin_amdgcn_exp2f(-y));
}
__device__ __forceinline__ float ftanh2(float y) {  // tanh(x), y = 2x*log2e
    return 1.0f - 2.0f * __builtin_amdgcn_rcpf(1.0f + __builtin_amdgcn_exp2f(y));
}
__device__ __forceinline__ float ftanhc(float c) {  // tanh(c), c true-scale
    return 1.0f - 2.0f * __builtin_amdgcn_rcpf(1.0f + __builtin_amdgcn_exp2f(c * (2.0f * L2E)));
}

// ---------------- prologue: frag-order + split + log2e prescale ----------------
__global__ void prep_weights(const float* __restrict__ whh0, const float* __restrict__ wih1,
                             const float* __restrict__ whh1, const float* __restrict__ wih2,
                             const float* __restrict__ whh2, const float* __restrict__ w1g)
{
    int gi = blockIdx.x * 256 + threadIdx.x;
    if (gi < 20480) {
        int m = gi >> 12;
        int rem = gi & 4095;
        int b = rem >> 6, l = rem & 63;
        int s = b & 1, ks = (b >> 1) & 1, g = (b >> 2) & 3, ug = b >> 4;
        int row = g * 64 + ug * 16 + (l & 15);
        int kb  = ks * 32 + (l >> 4) * 8;
        float fac = (g == 2) ? (2.0f * L2E) : L2E;
        const float* src = (m == 0) ? whh0 : (m == 1) ? wih1 : (m == 2) ? whh1
                         : (m == 3) ? wih2 : whh2;
        unsigned short o[8];
        #pragma unroll
        for (int i = 0; i < 8; ++i) {
            float v = src[row * 64 + kb + i] * fac;
            unsigned short hh = f2bf(v);
            if (s) {
                float r2 = v - __uint_as_float((unsigned int)hh << 16);
                hh = f2bf(r2);
            }
            o[i] = hh;
        }
        unsigned char* dst = g_wsbuf + m * 65536 + b * 1024 + l * 16;
        #pragma unroll
        for (int i = 0; i < 8; ++i) ((unsigned short*)dst)[i] = o[i];
    } else if (gi < 20992) {
        int g2 = gi - 20480;
        int b = g2 >> 6, l = g2 & 63;
        int s = b & 1, ks = (b >> 1) & 1, nt = b >> 2;
        int row = nt * 16 + (l & 15);
        int kb  = ks * 32 + (l >> 4) * 8;
        unsigned short o[8];
        #pragma unroll
        for (int i = 0; i < 8; ++i) {
            float v = w1g[row * 64 + kb + i];           // w1: unscaled
            unsigned short hh = f2bf(v);
            if (s) {
                float r2 = v - __uint_as_float((unsigned int)hh << 16);
                hh = f2bf(r2);
            }
            o[i] = hh;
        }
        unsigned char* dst = g_wsbuf + 327680 + b * 1024 + l * 16;
        #pragma unroll
        for (int i = 0; i < 8; ++i) ((unsigned short*)dst)[i] = o[i];
    }
}

#define MFMA_(A,B,C) __builtin_amdgcn_mfma_f32_16x16x32_bf16(A, B, C, 0, 0, 0)

// phase barrier: LDS-visibility only; global loads stay in flight (T4 counted-vmcnt
// happens automatically at the ds_write use site — only __syncthreads forces vmcnt(0))
#define BARX do { \
    asm volatile("s_waitcnt lgkmcnt(0)" ::: "memory"); \
    __builtin_amdgcn_s_barrier(); \
    __builtin_amdgcn_sched_barrier(0); \
    } while (0)

// 1024-thread staging: one dwordx4 per thread per 16KB quarter.
#define LOADQ(m, ks, s, R) \
    R = *(const bf16x8*)(g_wsbuf + (m) * 65536 + \
        (((tid >> 6) * 4 + (ks) * 2 + (s))) * 1024 + (tid & 63) * 16)
#define COMMITQ(R, p) \
    *(bf16x8*)(lds + QBUFP(p) + tid * 16) = R
#define LOADW1(R) do { if (tid < 512) \
    R = *(const bf16x8*)(g_wsbuf + 327680 + (tid >> 6) * 1024 + (tid & 63) * 16); } while (0)
#define COMMITW1(R, p) do { if (tid < 512) \
    *(bf16x8*)(lds + QBUFP(p) + tid * 16) = R; } while (0)

#define ACC_INIT(L) do { \
    _Pragma("unroll") for (int g_ = 0; g_ < 4; ++g_) { \
        float b_ = *(const float*)(lds + BGL_OFF + ((L) * 256 + g_ * 64 + u) * 4); \
        f32x4 t_ = {b_, b_, b_, b_}; \
        _Pragma("unroll") for (int mt_ = 0; mt_ < 2; ++mt_) acc[g_][mt_] = t_; \
    } } while (0)

#define GATE_HI(APL, ks, P) do { \
    bf16x8 bh_[4]; \
    _Pragma("unroll") for (int g_ = 0; g_ < 4; ++g_) \
        bh_[g_] = *(const bf16x8*)(lds + QBUFP(P) + (ug * 4 + g_) * 1024 + lane * 16); \
    _Pragma("unroll") for (int mt_ = 0; mt_ < 2; ++mt_) { \
        int ab_ = (((mbase + mt_ * 16 + l15) * 128 + (ks) * 64 + l4 * 16)) ^ rswz; \
        bf16x8 ah_ = *(const bf16x8*)(lds + PLANE(APL, 0) + ab_); \
        bf16x8 al_ = *(const bf16x8*)(lds + PLANE(APL, 1) + ab_); \
        _Pragma("unroll") for (int g_ = 0; g_ < 4; ++g_) { \
            acc[g_][mt_] = MFMA_(ah_, bh_[g_], acc[g_][mt_]); \
            acc[g_][mt_] = MFMA_(al_, bh_[g_], acc[g_][mt_]); \
        } } } while (0)

#define GATE_LO(APL, ks, P) do { \
    bf16x8 bl_[4]; \
    _Pragma("unroll") for (int g_ = 0; g_ < 4; ++g_) \
        bl_[g_] = *(const bf16x8*)(lds + QBUFP(P) + (ug * 4 + g_) * 1024 + lane * 16); \
    _Pragma("unroll") for (int mt_ = 0; mt_ < 2; ++mt_) { \
        int ab_ = (((mbase + mt_ * 16 + l15) * 128 + (ks) * 64 + l4 * 16)) ^ rswz; \
        bf16x8 ah_ = *(const bf16x8*)(lds + PLANE(APL, 0) + ab_); \
        _Pragma("unroll") for (int g_ = 0; g_ < 4; ++g_) \
            acc[g_][mt_] = MFMA_(ah_, bl_[g_], acc[g_][mt_]); \
    } } while (0)

#define CELLW(L, CARR) do { \
    _Pragma("unroll") for (int mt_ = 0; mt_ < 2; ++mt_) \
    _Pragma("unroll") for (int r_ = 0; r_ < 4; ++r_) { \
        float gi_ = fsig2(acc[0][mt_][r_]); \
        float gf_ = fsig2(acc[1][mt_][r_]); \
        float gg_ = ftanh2(acc[2][mt_][r_]); \
        float go_ = fsig2(acc[3][mt_][r_]); \
        float cn_ = gf_ * CARR[mt_ * 4 + r_] + gi_ * gg_; \
        CARR[mt_ * 4 + r_] = cn_; \
        float hn_ = go_ * ftanhc(cn_); \
        int e_ = mbase + mt_ * 16 + l4 * 4 + r_; \
        int wb_ = ((e_ * 128 + u * 2)) ^ ((e_ & 7) << 4); \
        unsigned short hh_ = f2bf(hn_); \
        float hf2_ = __uint_as_float((unsigned int)hh_ << 16); \
        unsigned short hl_ = f2bf(hn_ - hf2_); \
        *(unsigned short*)(lds + PLANE(L, 0) + wb_) = hh_; \
        *(unsigned short*)(lds + PLANE(L, 1) + wb_) = hl_; \
    } } while (0)

#define XPART do { \
    _Pragma("unroll") for (int mt_ = 0; mt_ < 2; ++mt_) \
    _Pragma("unroll") for (int r_ = 0; r_ < 4; ++r_) { \
        int e_ = mbase + mt_ * 16 + l4 * 4 + r_; \
        const float* xp_ = (const float*)(lds + XFB_OFF + e_ * 12); \
        float x0_ = xp_[0], x1_ = xp_[1], x2_ = xp_[2]; \
        _Pragma("unroll") for (int g_ = 0; g_ < 4; ++g_) { \
            const float* w0_ = (const float*)(lds + W0L_OFF + (g_ * 64 + u) * 12); \
            acc[g_][mt_][r_] += x0_ * w0_[0] + x1_ * w0_[1] + x2_ * w0_[2]; \
        } } } while (0)

#define MLP1(P) do { \
    int Mt_ = wv >> 1, half_ = wv & 1; \
    float b1_ = *(const float*)(lds + B1L_OFF + (half_ * 16 + l15) * 4); \
    f32x4 a1_ = {b1_, b1_, b1_, b1_}; \
    _Pragma("unroll") for (int ks_ = 0; ks_ < 2; ++ks_) { \
        int ab_ = (((Mt_ * 16 + l15) * 128 + ks_ * 64 + l4 * 16)) ^ rswz; \
        bf16x8 ah_ = *(const bf16x8*)(lds + PLANE(2, 0) + ab_); \
        bf16x8 al_ = *(const bf16x8*)(lds + PLANE(2, 1) + ab_); \
        bf16x8 wh_ = *(const bf16x8*)(lds + QBUFP(P) + ((half_ * 2 + ks_) * 2 + 0) * 1024 + lane * 16); \
        bf16x8 wl_ = *(const bf16x8*)(lds + QBUFP(P) + ((half_ * 2 + ks_) * 2 + 1) * 1024 + lane * 16); \
        a1_ = MFMA_(ah_, wh_, a1_); \
        a1_ = MFMA_(al_, wh_, a1_); \
        a1_ = MFMA_(ah_, wl_, a1_); \
    } \
    _Pragma("unroll") for (int r_ = 0; r_ < 4; ++r_) { \
        float y_ = a1_[r_]; y_ = (y_ >= 0.f) ? y_ : 0.01f * y_; \
        int e_ = Mt_ * 16 + l4 * 4 + r_; \
        *(unsigned short*)(lds + Y1_OFF + e_ * 68 + half_ * 32 + l15 * 2) = f2bf(y_); \
    } } while (0)

#define MLP2 do { \
    int e2_ = tid & 127, rg_ = tid >> 7; \
    float a2_[2]; \
    _Pragma("unroll") for (int m_ = 0; m_ < 2; ++m_) \
        a2_[m_] = *(const float*)(lds + B2L_OFF + (rg_ * 2 + m_) * 4); \
    _Pragma("unroll") for (int kd_ = 0; kd_ < 16; ++kd_) { \
        unsigned int d_ = *(const unsigned int*)(lds + Y1_OFF + e2_ * 68 + kd_ * 4); \
        float v0_ = bf2f_lo(d_), v1_ = bf2f_hi(d_); \
        _Pragma("unroll") for (int m_ = 0; m_ < 2; ++m_) { \
            unsigned int w_ = *(const unsigned int*)(lds + W2L_OFF + ((rg_ * 2 + m_) * 32 + kd_ * 2) * 2); \
            a2_[m_] = fmaf(v0_, bf2f_lo(w_), a2_[m_]); \
            a2_[m_] = fmaf(v1_, bf2f_hi(w_), a2_[m_]); \
        } } \
    _Pragma("unroll") for (int m_ = 0; m_ < 2; ++m_) { \
        float y_ = a2_[m_]; y_ = (y_ >= 0.f) ? y_ : 0.01f * y_; \
        *(unsigned short*)(lds + Y2_OFF + e2_ * 36 + (rg_ * 2 + m_) * 2) = f2bf(y_); \
    } } while (0)

#define MLP3_OUT do { \
    if (tid < 384) { \
        int e3_ = tid & 127, r3_ = tid >> 7; \
        float a3_ = *(const float*)(lds + B3L_OFF + r3_ * 4); \
        _Pragma("unroll") for (int kd_ = 0; kd_ < 8; ++kd_) { \
            unsigned int d_ = *(const unsigned int*)(lds + Y2_OFF + e3_ * 36 + kd_ * 4); \
            a3_ = fmaf(bf2f_lo(d_), *(const float*)(lds + W3L_OFF + (r3_ * 16 + kd_ * 2) * 4),     a3_); \
            a3_ = fmaf(bf2f_hi(d_), *(const float*)(lds + W3L_OFF + (r3_ * 16 + kd_ * 2 + 1) * 4), a3_); \
        } \
        float y_ = (a3_ >= 0.f) ? a3_ : 0.01f * a3_; \
        *(float*)(lds + XFB_OFF + e3_ * 12 + r3_ * 4) = y_; \
        *(float*)(lds + OUT_OFF + e3_ * 48 + (t & 3) * 12 + r3_ * 4) = y_; \
    } } while (0)

// ---------------- main persistent kernel ----------------
extern "C" __global__ void __launch_bounds__(NTHR)
__attribute__((amdgpu_waves_per_eu(4, 4)))
lstm_mfma(const float* __restrict__ noise,
          const float* __restrict__ wih0, const float* __restrict__ whh0,
          const float* __restrict__ bih0, const float* __restrict__ bhh0,
          const float* __restrict__ wih1, const float* __restrict__ whh1,
          const float* __restrict__ bih1, const float* __restrict__ bhh1,
          const float* __restrict__ wih2, const float* __restrict__ whh2,
          const float* __restrict__ bih2, const float* __restrict__ bhh2,
          const float* __restrict__ w1g, const float* __restrict__ b1g,
          const float* __restrict__ w2g, const float* __restrict__ b2g,
          const float* __restrict__ w3g, const float* __restrict__ b3g,
          const int* __restrict__ lenp, float* __restrict__ out)
{
    extern __shared__ unsigned char lds[];
    const int tid  = threadIdx.x;
    const int lane = tid & 63;
    const int wv   = tid >> 6;       // wave 0..15
    const int ug   = wv & 3;         // unit group (16 units)
    const int mh   = wv >> 2;        // M quarter 0..3
    const int l15  = lane & 15;
    const int l4   = lane >> 4;      // k-group
    const int u    = ug * 16 + l15;  // unit 0..63
    const int mbase = mh * 32;
    const int rswz  = (lane & 7) << 4;
    const int T = *lenp;
    const long eg0  = (long)blockIdx.x * BT;
    const long outs = 3L * T;

    // per-thread recurrent c state: 8 (unit,elem) pairs per layer
    float c0[8], c1[8], c2[8];
    #pragma unroll
    for (int i = 0; i < 8; ++i) { c0[i] = 0.f; c1[i] = 0.f; c2[i] = 0.f; }

    // staging registers (3-deep rotation)
    bf16x8 RA, RB, RC;

    // issue warmup loads early (q0,q1,q2)
    LOADQ(0, 0, 0, RA);
    LOADQ(0, 1, 0, RB);
    LOADQ(0, 0, 1, RC);

    // ---- LDS init ----
    for (int i = tid; i < 98304 / 4; i += NTHR) ((unsigned int*)lds)[i] = 0u;  // h planes = 0
    if (tid < BT) {
        #pragma unroll
        for (int k = 0; k < 3; ++k)
            *(float*)(lds + XFB_OFF + tid * 12 + k * 4) = noise[(eg0 + tid) * 3 + k];
    }
    if (tid < 512) *(unsigned short*)(lds + W2L_OFF + tid * 2) = f2bf(w2g[tid]);
    if (tid < 768) {                                   // bias sums, log2e-scaled
        int l = tid >> 8, r = tid & 255, g = r >> 6;
        float fac = (g == 2) ? (2.0f * L2E) : L2E;
        const float* bi = (l == 0) ? bih0 : ((l == 1) ? bih1 : bih2);
        const float* bh = (l == 0) ? bhh0 : ((l == 1) ? bhh1 : bhh2);
        *(float*)(lds + BGL_OFF + tid * 4) = (bi[r] + bh[r]) * fac;
    }
    if (tid < 768) {                                   // wih0, log2e-scaled
        int r = tid / 3, g = r >> 6;
        float fac = (g == 2) ? (2.0f * L2E) : L2E;
        *(float*)(lds + W0L_OFF + tid * 4) = wih0[tid] * fac;
    }
    if (tid < 32) *(float*)(lds + B1L_OFF + tid * 4) = b1g[tid];
    if (tid < 16) *(float*)(lds + B2L_OFF + tid * 4) = b2g[tid];
    if (tid < 3)  *(float*)(lds + B3L_OFF + tid * 4) = b3g[tid];
    if (tid < 48) *(float*)(lds + W3L_OFF + tid * 4) = w3g[tid];

    __syncthreads();                 // init visible (full drain, once)
    COMMITQ(RA, 0);                  // q0 -> buf0 (vmcnt auto-waited at use)
    __syncthreads();                 // buf0 ready

    f32x4 acc[4][2];

    #pragma unroll 1
    for (int t = 0; t < T; ++t) {
        const int bp = t & 1;
        // ---------------- layer 0: whh0 q0..q3 (A = plane0 old) ----------------
        COMMITQ(RB, bp ^ 1); LOADQ(0, 1, 1, RA);      // commit q1, load q3
        ACC_INIT(0); XPART;
        GATE_HI(0, 0, bp);                            // q0
        BARX;
        COMMITQ(RC, bp); LOADQ(1, 0, 0, RB);          // commit q2, load q4
        GATE_HI(0, 1, bp ^ 1);                        // q1
        BARX;
        COMMITQ(RA, bp ^ 1); LOADQ(1, 1, 0, RC);      // commit q3, load q5
        GATE_LO(0, 0, bp);                            // q2
        BARX;
        COMMITQ(RB, bp); LOADQ(1, 0, 1, RA);          // commit q4, load q6
        GATE_LO(0, 1, bp ^ 1);                        // q3
        BARX;
        CELLW(0, c0);                                 // h0 -> plane0
        BARX;
        // ---------------- layer 1: wih1 q4..q7 (A=plane0 new), whh1 q8..q11 (A=plane1 old) ----------------
        ACC_INIT(1);
        COMMITQ(RC, bp ^ 1); LOADQ(1, 1, 1, RB);      // commit q5, load q7
        GATE_HI(0, 0, bp);                            // q4
        BARX;
        COMMITQ(RA, bp); LOADQ(2, 0, 0, RC);          // commit q6, load q8
        GATE_HI(0, 1, bp ^ 1);                        // q5
        BARX;
        COMMITQ(RB, bp ^ 1); LOADQ(2, 1, 0, RA);      // commit q7, load q9
        GATE_LO(0, 0, bp);                            // q6
        BARX;
        COMMITQ(RC, bp); LOADQ(2, 0, 1, RB);          // commit q8, load q10
        GATE_LO(0, 1, bp ^ 1);                        // q7
        BARX;
        COMMITQ(RA, bp ^ 1); LOADQ(2, 1, 1, RC);      // commit q9, load q11
        GATE_HI(1, 0, bp);                            // q8
        BARX;
        COMMITQ(RB, bp); LOADQ(3, 0, 0, RA);          // commit q10, load q12
        GATE_HI(1, 1, bp ^ 1);                        // q9
        BARX;
        COMMITQ(RC, bp ^ 1); LOADQ(3, 1, 0, RB);      // commit q11, load q13
        GATE_LO(1, 0, bp);                            // q10
        BARX;
        COMMITQ(RA, bp); LOADQ(3, 0, 1, RC);          // commit q12, load q14
        GATE_LO(1, 1, bp ^ 1);                        // q11
        BARX;
        CELLW(1, c1);                                 // h1 -> plane1
        BARX;
        // ---------------- layer 2: wih2 q12..q15 (A=plane1 new), whh2 q16..q19 (A=plane2 old) ----------------
        ACC_INIT(2);
        COMMITQ(RB, bp ^ 1); LOADQ(3, 1, 1, RA);      // commit q13, load q15
        GATE_HI(1, 0, bp);                            // q12
        BARX;
        COMMITQ(RC, bp); LOADQ(4, 0, 0, RB);          // commit q14, load q16
        GATE_HI(1, 1, bp ^ 1);                        // q13
        BARX;
        COMMITQ(RA, bp ^ 1); LOADQ(4, 1, 0, RC);      // commit q15, load q17
        GATE_LO(1, 0, bp);                            // q14
        BARX;
        COMMITQ(RB, bp); LOADQ(4, 0, 1, RA);          // commit q16, load q18
        GATE_LO(1, 1, bp ^ 1);                        // q15
        BARX;
        COMMITQ(RC, bp ^ 1); LOADQ(4, 1, 1, RB);      // commit q17, load q19
        GATE_HI(2, 0, bp);                            // q16
        BARX;
        COMMITQ(RA, bp); LOADW1(RC);                  // commit q18, load q20 (w1)
        GATE_HI(2, 1, bp ^ 1);                        // q17
        BARX;
        COMMITQ(RB, bp ^ 1); LOADQ(0, 0, 0, RA);      // commit q19, load q0'
        GATE_LO(2, 0, bp);                            // q18
        BARX;
        COMMITW1(RC, bp); LOADQ(0, 1, 0, RB);         // commit q20(w1), load q1'
        GATE_LO(2, 1, bp ^ 1);                        // q19
        BARX;
        CELLW(2, c2);                                 // h2 -> plane2
        BARX;
        // ---------------- MLP head ----------------
        COMMITQ(RA, bp ^ 1); LOADQ(0, 0, 1, RC);      // commit q0', load q2'
        MLP1(bp);                                     // y1 via MFMA (A=plane2, B=w1)
        BARX;
        MLP2;                                         // y1 -> y2 (VALU)
        BARX;
        MLP3_OUT;                                     // y2 -> XFB + out ring
        if ((t & 3) == 3) {                           // flush 4 buffered steps
            BARX;
            long tb = t - 3;
            #pragma unroll
            for (int it = 0; it < 2; ++it) {
                int i = it * NTHR + tid;
                if (i < 1536) {
                    int e = i / 12, j = i - e * 12;
                    out[(eg0 + e) * outs + tb * 3 + j] =
                        *(const float*)(lds + OUT_OFF + e * 48 + j * 4);
                }
            }
        }
        BARX;                                         // step boundary
    }

    // tail flush (T not multiple of 4)
    int nst = T & 3;
    if (nst) {
        int nfl = BT * nst * 3;
        for (int i = tid; i < nfl; i += NTHR) {
            int e = i / (nst * 3), j = i - e * (nst * 3);
            out[(eg0 + e) * outs + (long)(T - nst) * 3 + j] =
                *(const float*)(lds + OUT_OFF + e * 48 + j * 4);
        }
    }
}

extern "C" void kernel_launch(void* const* d_in, const int* in_sizes, int n_in,
                              void* d_out, int out_size, void* d_ws, size_t ws_size,
                              hipStream_t stream)
{
    const float* noise = (const float*)d_in[0];
    const float* wih0  = (const float*)d_in[1];
    const float* whh0  = (const float*)d_in[2];
    const float* bih0  = (const float*)d_in[3];
    const float* bhh0  = (const float*)d_in[4];
    const float* wih1  = (const float*)d_in[5];
    const float* whh1  = (const float*)d_in[6];
    const float* bih1  = (const float*)d_in[7];
    const float* bhh1  = (const float*)d_in[8];
    const float* wih2  = (const float*)d_in[9];
    const float* whh2  = (const float*)d_in[10];
    const float* bih2  = (const float*)d_in[11];
    const float* bhh2  = (const float*)d_in[12];
    const float* w1g   = (const float*)d_in[13];
    const float* b1g   = (const float*)d_in[14];
    const float* w2g   = (const float*)d_in[15];
    const float* b2g   = (const float*)d_in[16];
    const float* w3g   = (const float*)d_in[17];
    const float* b3g   = (const float*)d_in[18];
    const int*   lenp  = (const int*)d_in[19];
    float* out = (float*)d_out;

    int B = in_sizes[0] / 3;              // 32768
    int grid = B / BT;                    // 256 blocks = 1 per CU

    prep_weights<<<82, 256, 0, stream>>>(whh0, wih1, whh1, wih2, whh2, w1g);

    hipFuncSetAttribute((const void*)lstm_mfma,
                        hipFuncAttributeMaxDynamicSharedMemorySize, LDS_TOTAL);
    lstm_mfma<<<grid, NTHR, LDS_TOTAL, stream>>>(
        noise, wih0, whh0, bih0, bhh0, wih1, whh1, bih1, bhh1,
        wih2, whh2, bih2, bhh2, w1g, b1g, w2g, b2g, w3g, b3g, lenp, out);
}